// Round 3
// baseline (1060.305 us; speedup 1.0000x reference)
//
#include <hip/hip_runtime.h>
#include <stdint.h>

typedef __bf16 bf16_t;
typedef __bf16 bf16x8 __attribute__((ext_vector_type(8)));
typedef __bf16 bf16x4 __attribute__((ext_vector_type(4)));
typedef float  f32x4  __attribute__((ext_vector_type(4)));

#define MFMA16(a, b, c) __builtin_amdgcn_mfma_f32_16x16x32_bf16((a), (b), (c), 0, 0, 0)

// Async global->LDS 16B/lane. LDS dest is wave-uniform base + lane*16; our
// lds ptr is computed as base + lane*16, matching the HW contract (m97/m104).
__device__ __forceinline__ void load_lds16(const bf16_t* g, bf16_t* l)
{
    __builtin_amdgcn_global_load_lds(
        (const __attribute__((address_space(1))) uint32_t*)(uintptr_t)g,
        (__attribute__((address_space(3))) uint32_t*)(uint32_t)(uintptr_t)l,
        16, 0, 0);
}

// Stage 2x16B per thread into LDS with T2 inverse-swizzled global source.
// LDS linear slot u*16B holds global[row][ (x ^ ((row&7)<<3)) ] for x in the
// 8-elem group; readers apply the same XOR (involution, rule 21).
__device__ __forceinline__ void lds_stage2(const bf16_t* __restrict__ Gsrc,
                                           bf16_t* Ldst, int u0,
                                           int tid, int K, int k0)
{
#pragma unroll
    for (int l = 0; l < 2; ++l) {
        int u = u0 + l * 512 + tid;
        int row = u >> 3;
        int col = (((u & 7) ^ (row & 7)) << 3);
        load_lds16(Gsrc + (size_t)row * K + k0 + col, Ldst + u * 8);
    }
}

// ---------------------------------------------------------------------------
// Weight convert fp32 -> bf16, 8 elems/thread
// ---------------------------------------------------------------------------
__global__ __launch_bounds__(256)
void wconv(const float* __restrict__ X, bf16_t* __restrict__ Y, int n)
{
    int i = (blockIdx.x * 256 + threadIdx.x) * 8;
    if (i >= n) return;
    f32x4 a = *(const f32x4*)(X + i);
    f32x4 b = *(const f32x4*)(X + i + 4);
    bf16x8 y;
#pragma unroll
    for (int e = 0; e < 4; ++e) { y[e] = (bf16_t)a[e]; y[e + 4] = (bf16_t)b[e]; }
    *(bf16x8*)(Y + i) = y;
}

// ---------------------------------------------------------------------------
// RMSNorm (fp32 in -> bf16 out)
// ---------------------------------------------------------------------------
__global__ __launch_bounds__(256)
void rmsnorm_f32(const float* __restrict__ X, const float* __restrict__ Wt,
                 bf16_t* __restrict__ Y)
{
    __shared__ float red[4];
    const int tid = threadIdx.x;
    const size_t row = blockIdx.x;
    const float* x = X + row * 2048;

    f32x4 x0 = *(const f32x4*)(x + tid * 8);
    f32x4 x1 = *(const f32x4*)(x + tid * 8 + 4);
    float ss = 0.f;
#pragma unroll
    for (int e = 0; e < 4; ++e) ss += x0[e] * x0[e] + x1[e] * x1[e];
#pragma unroll
    for (int off = 32; off; off >>= 1) ss += __shfl_xor(ss, off, 64);
    if ((tid & 63) == 0) red[tid >> 6] = ss;
    __syncthreads();
    float tot = red[0] + red[1] + red[2] + red[3];
    float scale = rsqrtf(tot * (1.f / 2048.f) + 1e-6f);

    f32x4 w0 = *(const f32x4*)(Wt + tid * 8);
    f32x4 w1 = *(const f32x4*)(Wt + tid * 8 + 4);
    bf16x8 yv;
#pragma unroll
    for (int e = 0; e < 4; ++e) {
        yv[e]     = (bf16_t)(x0[e] * scale * w0[e]);
        yv[e + 4] = (bf16_t)(x1[e] * scale * w1[e]);
    }
    *(bf16x8*)(Y + row * 2048 + tid * 8) = yv;
}

// ---------------------------------------------------------------------------
// RMSNorm (bf16 in -> bf16 out), fp32 gamma
// ---------------------------------------------------------------------------
__global__ __launch_bounds__(256)
void rmsnorm_bf16(const bf16_t* __restrict__ X, const float* __restrict__ Wt,
                  bf16_t* __restrict__ Y)
{
    __shared__ float red[4];
    const int tid = threadIdx.x;
    const size_t row = blockIdx.x;

    bf16x8 xv = *(const bf16x8*)(X + row * 2048 + tid * 8);
    float xf[8];
    float ss = 0.f;
#pragma unroll
    for (int e = 0; e < 8; ++e) { xf[e] = (float)xv[e]; ss += xf[e] * xf[e]; }
#pragma unroll
    for (int off = 32; off; off >>= 1) ss += __shfl_xor(ss, off, 64);
    if ((tid & 63) == 0) red[tid >> 6] = ss;
    __syncthreads();
    float tot = red[0] + red[1] + red[2] + red[3];
    float scale = rsqrtf(tot * (1.f / 2048.f) + 1e-6f);

    f32x4 w0 = *(const f32x4*)(Wt + tid * 8);
    f32x4 w1 = *(const f32x4*)(Wt + tid * 8 + 4);
    bf16x8 yv;
#pragma unroll
    for (int e = 0; e < 4; ++e) {
        yv[e]     = (bf16_t)(xf[e] * scale * w0[e]);
        yv[e + 4] = (bf16_t)(xf[e + 4] * scale * w1[e]);
    }
    *(bf16x8*)(Y + row * 2048 + tid * 8) = yv;
}

// ---------------------------------------------------------------------------
// FAST PATH GEMM (pure bf16, global_load_lds staging, m97 structure).
// Used only in the middle tier for K/V projections.
// ---------------------------------------------------------------------------
__global__ __launch_bounds__(256, 2)
void gemm_bb(const bf16_t* __restrict__ A, const bf16_t* __restrict__ W,
             const float* __restrict__ Rf, const bf16_t* __restrict__ Rb,
             bf16_t* __restrict__ Cb, float* __restrict__ Cf,
             int M, int N, int K, int mode)
{
    __shared__ bf16_t As[128 * 64];
    __shared__ bf16_t Ws[128 * 64];

    const int tid  = threadIdx.x;
    const int lane = tid & 63, wave = tid >> 6;
    const int quad = lane >> 4, l16 = lane & 15;
    const int m0 = blockIdx.y * 128, n0 = blockIdx.x * 128;
    const int wm = (wave >> 1) * 64, wn = (wave & 1) * 64;

    const bf16_t* Ab = A + (size_t)(m0 + (tid >> 3)) * K + ((tid & 7) << 3);
    const bf16_t* Wb = W + (size_t)(n0 + (tid >> 3)) * K + ((tid & 7) << 3);

    f32x4 acc[4][4] = {};

    for (int k0 = 0; k0 < K; k0 += 64) {
        __syncthreads();
#pragma unroll
        for (int i = 0; i < 4; ++i) {
            load_lds16(Ab + (size_t)(i * 32) * K + k0, As + (i * 256 + tid) * 8);
            load_lds16(Wb + (size_t)(i * 32) * K + k0, Ws + (i * 256 + tid) * 8);
        }
        __syncthreads();

#pragma unroll
        for (int ks = 0; ks < 64; ks += 32) {
            bf16x8 af[4], bfr[4];
#pragma unroll
            for (int i = 0; i < 4; ++i)
                af[i] = *(const bf16x8*)(As + (wm + i * 16 + l16) * 64 + ks + quad * 8);
#pragma unroll
            for (int j = 0; j < 4; ++j)
                bfr[j] = *(const bf16x8*)(Ws + (wn + j * 16 + l16) * 64 + ks + quad * 8);
#pragma unroll
            for (int i = 0; i < 4; ++i)
#pragma unroll
                for (int j = 0; j < 4; ++j)
                    acc[i][j] = MFMA16(af[i], bfr[j], acc[i][j]);
        }
    }

#pragma unroll
    for (int i = 0; i < 4; ++i)
#pragma unroll
        for (int j = 0; j < 4; ++j)
#pragma unroll
            for (int r = 0; r < 4; ++r) {
                size_t row = (size_t)(m0 + wm + i * 16 + quad * 4 + r);
                size_t col = (size_t)(n0 + wn + j * 16 + l16);
                float v = acc[i][j][r];
                if (mode == 1) v += Rf[row * (size_t)N + col];
                if (mode == 2)
                    Cf[row * (size_t)N + col] = v + (float)Rb[row * (size_t)N + col];
                else
                    Cb[row * (size_t)N + col] = (bf16_t)v;
            }
}

// ---------------------------------------------------------------------------
// 8-phase GEMM (T1+T2+T3+T4+T5), tile 256x128, 8 waves as 4M x 2N
// (per-wave 64x64), double-buffered 96 KiB LDS, balanced 2 phases/K-tile
// (8 ds_reads -> 16 MFMA each), stage pairs at top/P0/P1, counted vmcnt(2).
// Grid = (M/256)*nbx blocks (must be %8==0); M assumed 4096 (16 M-panels).
// mode 0: Cb=acc | 1: Cb=acc+Rf(f32) | 2: Cf=acc+Rb(bf16) | 4: Cb=silu(Rb)*acc
// ---------------------------------------------------------------------------
__global__ __launch_bounds__(512, 2)
void gemm8(const bf16_t* __restrict__ A, const bf16_t* __restrict__ W,
           const float* __restrict__ Rf, const bf16_t* __restrict__ Rb,
           bf16_t* __restrict__ Cb, float* __restrict__ Cf,
           int M, int N, int K, int nbx, int mode)
{
    __shared__ bf16_t As[2][256 * 64];   // 64 KiB
    __shared__ bf16_t Ws[2][128 * 64];   // 32 KiB

    const int tid  = threadIdx.x;
    const int lane = tid & 63, wave = tid >> 6;
    const int quad = lane >> 4, l16 = lane & 15;
    const int wr = wave >> 1, wc = wave & 1;   // 4M x 2N wave grid

    // T1: bijective XCD swizzle (requires nwg % 8 == 0), W-panel-resident
    // ordering: consecutive swz share bxn -> W panel stays in the XCD's L2
    // across 16 M-blocks; A panels stream from L3 (shared by all XCDs).
    const int lid = (int)blockIdx.x;
    const int nwg = (M >> 8) * nbx;
    const int q   = nwg >> 3;
    const int swz = (lid & 7) * q + (lid >> 3);
    const int bxn = swz >> 4;                      // 0..nbx-1
    const int bym = swz & 15;                      // 0..15
    const int m0 = bym * 256, n0 = bxn * 128;

    const bf16_t* Ab = A + (size_t)m0 * K;
    const bf16_t* Wb = W + (size_t)n0 * K;

    const int xsw  = (l16 & 7) << 3;               // T2 read-side XOR (elems)
    const int aoff = (wr * 64 + l16) * 64;
    const int boff = (wc * 64 + l16) * 64;

    f32x4 acc[4][4] = {};

    // prologue: stage tile 0 fully (6 loads/thread)
    lds_stage2(Ab, As[0], 0,    tid, K, 0);
    lds_stage2(Ab, As[0], 1024, tid, K, 0);
    lds_stage2(Wb, Ws[0], 0,    tid, K, 0);

    const int NT = K >> 6;
    for (int t = 0; t < NT; ++t) {
        const int b  = t & 1;
        const int kn = (t + 1) << 6;
        const bool pf = (t + 1 < NT);
        bf16_t* An = As[1 - b];
        bf16_t* Wn = Ws[1 - b];

        if (pf) {
            lds_stage2(Ab, An, 0, tid, K, kn);
            // T4: drain tile t's 6 loads; the 2 just issued stay in flight.
            asm volatile("s_waitcnt vmcnt(2)" ::: "memory");
        } else {
            asm volatile("s_waitcnt vmcnt(0)" ::: "memory");
        }
        __builtin_amdgcn_s_barrier();   // tile t visible to ALL waves

        const bf16_t* Asb = As[b];
        const bf16_t* Wsb = Ws[b];

#pragma unroll
        for (int ks = 0; ks < 2; ++ks) {
            const int kxo = (ks * 32 + quad * 8) ^ xsw;
            bf16x8 af[4], bf_[4];
#pragma unroll
            for (int i = 0; i < 4; ++i)
                af[i] = *(const bf16x8*)(Asb + aoff + i * 1024 + kxo);
#pragma unroll
            for (int j = 0; j < 4; ++j)
                bf_[j] = *(const bf16x8*)(Wsb + boff + j * 1024 + kxo);
            if (pf) {
                if (ks == 0) lds_stage2(Ab, An, 1024, tid, K, kn);
                else         lds_stage2(Wb, Wn, 0,    tid, K, kn);
            }
            __builtin_amdgcn_s_barrier();
            __builtin_amdgcn_s_setprio(1);
#pragma unroll
            for (int i = 0; i < 4; ++i)
#pragma unroll
                for (int j = 0; j < 4; ++j)
                    acc[i][j] = MFMA16(af[i], bf_[j], acc[i][j]);
            __builtin_amdgcn_s_setprio(0);
            __builtin_amdgcn_s_barrier();
        }
    }

#pragma unroll
    for (int i = 0; i < 4; ++i)
#pragma unroll
        for (int j = 0; j < 4; ++j)
#pragma unroll
            for (int r = 0; r < 4; ++r) {
                size_t row = (size_t)(m0 + wr * 64 + i * 16 + quad * 4 + r);
                size_t col = (size_t)(n0 + wc * 64 + j * 16 + l16);
                float v = acc[i][j][r];
                if (mode == 1) v += Rf[row * (size_t)N + col];
                if (mode == 4) {
                    float g = (float)Rb[row * (size_t)N + col];
                    float sig = 1.f / (1.f + __expf(fminf(-g, 80.f)));
                    v *= g * sig;
                }
                if (mode == 2)
                    Cf[row * (size_t)N + col] = v + (float)Rb[row * (size_t)N + col];
                else
                    Cb[row * (size_t)N + col] = (bf16_t)v;
            }
}

// ---------------------------------------------------------------------------
// Fused gate+up SwiGLU GEMM (middle tier only), round-2 version.
// ---------------------------------------------------------------------------
__global__ __launch_bounds__(512, 2)
void gateup8(const bf16_t* __restrict__ A, const bf16_t* __restrict__ G,
             const bf16_t* __restrict__ U, bf16_t* __restrict__ C,
             int M, int N, int K)
{
    __shared__ bf16_t As[2][256 * 64];   // 64 KiB
    __shared__ bf16_t Gs[2][128 * 64];   // 32 KiB
    __shared__ bf16_t Us[2][128 * 64];   // 32 KiB

    const int tid  = threadIdx.x;
    const int lane = tid & 63;
    const int wave = tid >> 6;
    const int quad = lane >> 4, l16 = lane & 15;
    const int wr = wave >> 2, wc = wave & 3;      // 2M x 4N wave grid

    const int lid = (int)blockIdx.x;
    const int nwg = (M >> 8) * (N >> 7);          // 16 * 44 = 704
    const int cpx = nwg >> 3;                     // 88
    const int swz = (lid & 7) * cpx + (lid >> 3);
    const int bxn = swz >> 4;                     // N-block (44)
    const int bym = swz & 15;                     // M-block (16)
    const int m0 = bym * 256, n0 = bxn * 128;

    const bf16_t* Ab = A + (size_t)m0 * K;
    const bf16_t* Gb = G + (size_t)n0 * K;
    const bf16_t* Ub = U + (size_t)n0 * K;

    const int xsw  = (l16 & 7) << 3;              // T2 read-side XOR (elems)
    const int aoff = (wr * 128 + l16) * 64;
    const int boff = (wc * 32 + l16) * 64;

    f32x4 accg[8][2] = {};
    f32x4 accu[8][2] = {};

    lds_stage2(Ab, As[0], 0,    tid, K, 0);
    lds_stage2(Ab, As[0], 1024, tid, K, 0);
    lds_stage2(Gb, Gs[0], 0,    tid, K, 0);
    lds_stage2(Ub, Us[0], 0,    tid, K, 0);

    const int NT = K >> 6;                        // 32 K-tiles
    for (int t = 0; t < NT; ++t) {
        const int b  = t & 1;
        const int kn = (t + 1) << 6;
        const bool pf = (t + 1 < NT);
        bf16_t* An = As[1 - b];
        bf16_t* Gn = Gs[1 - b];
        bf16_t* Un = Us[1 - b];

        if (pf) {
            lds_stage2(Ab, An, 0, tid, K, kn);
            asm volatile("s_waitcnt vmcnt(2)" ::: "memory");
        } else {
            asm volatile("s_waitcnt vmcnt(0)" ::: "memory");
        }
        __builtin_amdgcn_s_barrier();

        const bf16_t* Asb = As[b];
        const bf16_t* Gsb = Gs[b];
        const bf16_t* Usb = Us[b];

        bf16x8 af[4], bg[2], bu[2];

        // ---- P0: ks=0, A rows lo ----
        {
            const int kxo = (quad * 8) ^ xsw;
#pragma unroll
            for (int i = 0; i < 4; ++i)
                af[i] = *(const bf16x8*)(Asb + aoff + i * 1024 + kxo);
#pragma unroll
            for (int j = 0; j < 2; ++j) {
                bg[j] = *(const bf16x8*)(Gsb + boff + j * 1024 + kxo);
                bu[j] = *(const bf16x8*)(Usb + boff + j * 1024 + kxo);
            }
        }
        if (pf) lds_stage2(Ab, An, 1024, tid, K, kn);
        __builtin_amdgcn_s_barrier();
        __builtin_amdgcn_s_setprio(1);
#pragma unroll
        for (int i = 0; i < 4; ++i)
#pragma unroll
            for (int j = 0; j < 2; ++j) {
                accg[i][j] = MFMA16(af[i], bg[j], accg[i][j]);
                accu[i][j] = MFMA16(af[i], bu[j], accu[i][j]);
            }
        __builtin_amdgcn_s_setprio(0);
        __builtin_amdgcn_s_barrier();

        // ---- P1: ks=0, A rows hi ----
        {
            const int kxo = (quad * 8) ^ xsw;
#pragma unroll
            for (int i = 0; i < 4; ++i)
                af[i] = *(const bf16x8*)(Asb + aoff + (i + 4) * 1024 + kxo);
        }
        if (pf) lds_stage2(Gb, Gn, 0, tid, K, kn);
        __builtin_amdgcn_s_barrier();
        __builtin_amdgcn_s_setprio(1);
#pragma unroll
        for (int i = 0; i < 4; ++i)
#pragma unroll
            for (int j = 0; j < 2; ++j) {
                accg[i + 4][j] = MFMA16(af[i], bg[j], accg[i + 4][j]);
                accu[i + 4][j] = MFMA16(af[i], bu[j], accu[i + 4][j]);
            }
        __builtin_amdgcn_s_setprio(0);
        __builtin_amdgcn_s_barrier();

        // ---- P2: ks=1, A rows lo ----
        {
            const int kxo = (32 + quad * 8) ^ xsw;
#pragma unroll
            for (int i = 0; i < 4; ++i)
                af[i] = *(const bf16x8*)(Asb + aoff + i * 1024 + kxo);
#pragma unroll
            for (int j = 0; j < 2; ++j) {
                bg[j] = *(const bf16x8*)(Gsb + boff + j * 1024 + kxo);
                bu[j] = *(const bf16x8*)(Usb + boff + j * 1024 + kxo);
            }
        }
        if (pf) lds_stage2(Ub, Un, 0, tid, K, kn);
        __builtin_amdgcn_s_barrier();
        __builtin_amdgcn_s_setprio(1);
#pragma unroll
        for (int i = 0; i < 4; ++i)
#pragma unroll
            for (int j = 0; j < 2; ++j) {
                accg[i][j] = MFMA16(af[i], bg[j], accg[i][j]);
                accu[i][j] = MFMA16(af[i], bu[j], accu[i][j]);
            }
        __builtin_amdgcn_s_setprio(0);
        __builtin_amdgcn_s_barrier();

        // ---- P3: ks=1, A rows hi ----
        {
            const int kxo = (32 + quad * 8) ^ xsw;
#pragma unroll
            for (int i = 0; i < 4; ++i)
                af[i] = *(const bf16x8*)(Asb + aoff + (i + 4) * 1024 + kxo);
        }
        __builtin_amdgcn_s_barrier();
        __builtin_amdgcn_s_setprio(1);
#pragma unroll
        for (int i = 0; i < 4; ++i)
#pragma unroll
            for (int j = 0; j < 2; ++j) {
                accg[i + 4][j] = MFMA16(af[i], bg[j], accg[i + 4][j]);
                accu[i + 4][j] = MFMA16(af[i], bu[j], accu[i + 4][j]);
            }
        __builtin_amdgcn_s_setprio(0);
        __builtin_amdgcn_s_barrier();
    }

#pragma unroll
    for (int i = 0; i < 8; ++i)
#pragma unroll
        for (int j = 0; j < 2; ++j)
#pragma unroll
            for (int r = 0; r < 4; ++r) {
                size_t row = (size_t)(m0 + wr * 128 + i * 16 + quad * 4 + r);
                size_t col = (size_t)(n0 + wc * 32 + j * 16 + l16);
                float g = accg[i][j][r];
                float u = accu[i][j][r];
                float sig = 1.f / (1.f + __expf(fminf(-g, 80.f)));
                C[row * (size_t)N + col] = (bf16_t)(g * sig * u);
            }
}

// ---------------------------------------------------------------------------
// FALLBACK GEMM (round-4 path, fp32 weights staged in registers)
// ---------------------------------------------------------------------------
__global__ __launch_bounds__(256, 2)
void gemm_bt(const bf16_t* __restrict__ A, const float* __restrict__ W,
             const float* __restrict__ Rf, const bf16_t* __restrict__ Rb,
             bf16_t* __restrict__ Cb, float* __restrict__ Cf,
             int M, int N, int K, int mode)
{
    __shared__ bf16_t As[128 * 64];
    __shared__ bf16_t Ws[128 * 64];

    const int tid  = threadIdx.x;
    const int lane = tid & 63, wave = tid >> 6;
    const int quad = lane >> 4, l16 = lane & 15;
    const int m0 = blockIdx.y * 128, n0 = blockIdx.x * 128;
    const int wm = (wave >> 1) * 64, wn = (wave & 1) * 64;

    f32x4 acc[4][4] = {};

    for (int k0 = 0; k0 < K; k0 += 64) {
        bf16x8 ra[4];
        bf16x4 rw[8];
#pragma unroll
        for (int i = 0; i < 4; ++i) {
            int u = i * 256 + tid;
            int r = u >> 3, c = (u & 7) << 3;
            ra[i] = *(const bf16x8*)(A + (size_t)(m0 + r) * K + k0 + c);
        }
#pragma unroll
        for (int i = 0; i < 8; ++i) {
            int u = i * 256 + tid;
            int r = u >> 4, c = (u & 15) << 2;
            f32x4 w4 = *(const f32x4*)(W + (size_t)(n0 + r) * K + k0 + c);
#pragma unroll
            for (int e = 0; e < 4; ++e) rw[i][e] = (bf16_t)w4[e];
        }
        __syncthreads();
#pragma unroll
        for (int i = 0; i < 4; ++i)
            *(bf16x8*)(As + (i * 256 + tid) * 8) = ra[i];
#pragma unroll
        for (int i = 0; i < 8; ++i)
            *(bf16x4*)(Ws + (i * 256 + tid) * 4) = rw[i];
        __syncthreads();

#pragma unroll
        for (int ks = 0; ks < 64; ks += 32) {
            bf16x8 af[4], bfr[4];
#pragma unroll
            for (int i = 0; i < 4; ++i)
                af[i] = *(const bf16x8*)(As + (wm + i * 16 + l16) * 64 + ks + quad * 8);
#pragma unroll
            for (int j = 0; j < 4; ++j)
                bfr[j] = *(const bf16x8*)(Ws + (wn + j * 16 + l16) * 64 + ks + quad * 8);
#pragma unroll
            for (int i = 0; i < 4; ++i)
#pragma unroll
                for (int j = 0; j < 4; ++j)
                    acc[i][j] = MFMA16(af[i], bfr[j], acc[i][j]);
        }
    }

#pragma unroll
    for (int i = 0; i < 4; ++i)
#pragma unroll
        for (int j = 0; j < 4; ++j)
#pragma unroll
            for (int r = 0; r < 4; ++r) {
                size_t row = (size_t)(m0 + wm + i * 16 + quad * 4 + r);
                size_t col = (size_t)(n0 + wn + j * 16 + l16);
                float v = acc[i][j][r];
                if (mode == 1) v += Rf[row * (size_t)N + col];
                if (mode == 2)
                    Cf[row * (size_t)N + col] = v + (float)Rb[row * (size_t)N + col];
                else
                    Cb[row * (size_t)N + col] = (bf16_t)v;
            }
}

// ---------------------------------------------------------------------------
// FALLBACK fused gate+up (round-4 path, fp32 weights)
// ---------------------------------------------------------------------------
__global__ __launch_bounds__(256, 2)
void gemm_gateup(const bf16_t* __restrict__ A, const float* __restrict__ G,
                 const float* __restrict__ U, bf16_t* __restrict__ C,
                 int M, int N, int K)
{
    __shared__ bf16_t As[128 * 64];
    __shared__ bf16_t Gs[128 * 64];
    __shared__ bf16_t Us[128 * 64];

    const int tid  = threadIdx.x;
    const int lane = tid & 63, wave = tid >> 6;
    const int quad = lane >> 4, l16 = lane & 15;
    const int m0 = blockIdx.y * 128, n0 = blockIdx.x * 128;
    const int wm = (wave >> 1) * 64, wn = (wave & 1) * 64;

    f32x4 accg[4][4] = {};
    f32x4 accu[4][4] = {};

    for (int k0 = 0; k0 < K; k0 += 64) {
        bf16x8 ra[4];
        bf16x4 rg[8], ru[8];
#pragma unroll
        for (int i = 0; i < 4; ++i) {
            int u = i * 256 + tid;
            int r = u >> 3, c = (u & 7) << 3;
            ra[i] = *(const bf16x8*)(A + (size_t)(m0 + r) * K + k0 + c);
        }
#pragma unroll
        for (int i = 0; i < 8; ++i) {
            int u = i * 256 + tid;
            int r = u >> 4, c = (u & 15) << 2;
            f32x4 g4 = *(const f32x4*)(G + (size_t)(n0 + r) * K + k0 + c);
            f32x4 u4 = *(const f32x4*)(U + (size_t)(n0 + r) * K + k0 + c);
#pragma unroll
            for (int e = 0; e < 4; ++e) { rg[i][e] = (bf16_t)g4[e]; ru[i][e] = (bf16_t)u4[e]; }
        }
        __syncthreads();
#pragma unroll
        for (int i = 0; i < 4; ++i)
            *(bf16x8*)(As + (i * 256 + tid) * 8) = ra[i];
#pragma unroll
        for (int i = 0; i < 8; ++i) {
            *(bf16x4*)(Gs + (i * 256 + tid) * 4) = rg[i];
            *(bf16x4*)(Us + (i * 256 + tid) * 4) = ru[i];
        }
        __syncthreads();

#pragma unroll
        for (int ks = 0; ks < 64; ks += 32) {
            bf16x8 af[4], bg[4], bu[4];
#pragma unroll
            for (int i = 0; i < 4; ++i)
                af[i] = *(const bf16x8*)(As + (wm + i * 16 + l16) * 64 + ks + quad * 8);
#pragma unroll
            for (int j = 0; j < 4; ++j) {
                bg[j] = *(const bf16x8*)(Gs + (wn + j * 16 + l16) * 64 + ks + quad * 8);
                bu[j] = *(const bf16x8*)(Us + (wn + j * 16 + l16) * 64 + ks + quad * 8);
            }
#pragma unroll
            for (int i = 0; i < 4; ++i)
#pragma unroll
                for (int j = 0; j < 4; ++j) {
                    accg[i][j] = MFMA16(af[i], bg[j], accg[i][j]);
                    accu[i][j] = MFMA16(af[i], bu[j], accu[i][j]);
                }
        }
    }

#pragma unroll
    for (int i = 0; i < 4; ++i)
#pragma unroll
        for (int j = 0; j < 4; ++j)
#pragma unroll
            for (int r = 0; r < 4; ++r) {
                size_t row = (size_t)(m0 + wm + i * 16 + quad * 4 + r);
                size_t col = (size_t)(n0 + wn + j * 16 + l16);
                float g = accg[i][j][r];
                float u = accu[i][j][r];
                float sig = 1.f / (1.f + __expf(fminf(-g, 80.f)));
                C[row * (size_t)N + col] = (bf16_t)(g * sig * u);
            }
}

// ---------------------------------------------------------------------------
// Flash attention fwd. kvs = row stride of K/V buffers (1024 separate,
// 2048 interleaved KV from the fused projection).
// ---------------------------------------------------------------------------
__global__ __launch_bounds__(256, 2)
void attn_fwd(const bf16_t* __restrict__ Q, const bf16_t* __restrict__ Kg,
              const bf16_t* __restrict__ Vg, bf16_t* __restrict__ O, int kvs)
{
    __shared__ bf16_t Ks[64 * 128];
    __shared__ bf16_t Vt[128 * 64];      // Vt[d][k], k-blocks XOR-swizzled by d&7
    __shared__ bf16_t Pl[4][16 * 72];    // padded stride 72

    const int tid  = threadIdx.x;
    const int lane = tid & 63, wave = tid >> 6;
    const int quad = lane >> 4, l16 = lane & 15;
    const int bh = blockIdx.y, b = bh >> 4, h = bh & 15;

    const bf16_t* Qh = Q  + (size_t)b * 2048 * 2048 + (size_t)h * 128;
    const bf16_t* Kh = Kg + (size_t)b * 2048 * kvs + (size_t)(h >> 1) * 128;
    const bf16_t* Vh = Vg + (size_t)b * 2048 * kvs + (size_t)(h >> 1) * 128;

    const float scale = 0.08838834764831845f;   // 1/sqrt(128)

#pragma unroll 1
    for (int pass = 0; pass < 2; ++pass) {
        const int qt = pass ? (31 - (int)blockIdx.x) : (int)blockIdx.x;
        const int q0 = qt * 64;

        bf16x8 aq[4];
#pragma unroll
        for (int ks = 0; ks < 4; ++ks)
            aq[ks] = *(const bf16x8*)(Qh + (size_t)(q0 + wave * 16 + l16) * 2048 + ks * 32 + quad * 8);

        float m_r[4] = { -30000.f, -30000.f, -30000.f, -30000.f };
        float l_r[4] = { 0.f, 0.f, 0.f, 0.f };
        f32x4 acc_o[8] = {};

        const int ntiles = qt + 1;

        for (int t = 0; t < ntiles; ++t) {
            const int kv0 = t * 64;
            __syncthreads();
#pragma unroll
            for (int i = 0; i < 4; ++i) {
                int u = i * 256 + tid;
                int rk = u >> 4, c = (u & 15) << 3;
                *(bf16x8*)(Ks + u * 8) =
                    *(const bf16x8*)(Kh + (size_t)(kv0 + rk) * kvs + c);
            }
#pragma unroll
            for (int it = 0; it < 4; ++it) {
                int v = it * 256 + tid;
                int d = v & 127, kb = v >> 7;
                bf16x8 vt8;
#pragma unroll
                for (int j = 0; j < 8; ++j)
                    vt8[j] = Vh[(size_t)(kv0 + kb * 8 + j) * kvs + d];
                *(bf16x8*)(Vt + d * 64 + ((kb ^ (d & 7)) << 3)) = vt8;
            }
            __syncthreads();

            f32x4 accs[4] = {};
#pragma unroll
            for (int ks = 0; ks < 4; ++ks)
#pragma unroll
                for (int j = 0; j < 4; ++j) {
                    bf16x8 bk = *(const bf16x8*)(Ks + (j * 16 + l16) * 128 + ks * 32 + quad * 8);
                    accs[j] = MFMA16(aq[ks], bk, accs[j]);
                }

#pragma unroll
            for (int r = 0; r < 4; ++r) {
                const int qrow = q0 + wave * 16 + quad * 4 + r;
                float s[4];
                float mx = -30000.f;
#pragma unroll
                for (int j = 0; j < 4; ++j) {
                    s[j] = accs[j][r] * scale;
                    if (kv0 + j * 16 + l16 > qrow) s[j] = -30000.f;
                    mx = fmaxf(mx, s[j]);
                }
                mx = fmaxf(mx, __shfl_xor(mx, 1, 64));
                mx = fmaxf(mx, __shfl_xor(mx, 2, 64));
                mx = fmaxf(mx, __shfl_xor(mx, 4, 64));
                mx = fmaxf(mx, __shfl_xor(mx, 8, 64));
                float mnew  = fmaxf(m_r[r], mx);
                float alpha = __expf(fmaxf(m_r[r] - mnew, -80.f));
                float rs = 0.f;
#pragma unroll
                for (int j = 0; j < 4; ++j) {
                    float p = __expf(fmaxf(s[j] - mnew, -80.f));
                    rs += p;
                    Pl[wave][(quad * 4 + r) * 72 + j * 16 + l16] = (bf16_t)p;
                }
                rs += __shfl_xor(rs, 1, 64);
                rs += __shfl_xor(rs, 2, 64);
                rs += __shfl_xor(rs, 4, 64);
                rs += __shfl_xor(rs, 8, 64);
                l_r[r] = l_r[r] * alpha + rs;
                m_r[r] = mnew;
#pragma unroll
                for (int nt = 0; nt < 8; ++nt) acc_o[nt][r] *= alpha;
            }

            __syncthreads();

#pragma unroll
            for (int ks2 = 0; ks2 < 2; ++ks2) {
                bf16x8 ap = *(const bf16x8*)(&Pl[wave][l16 * 72 + ks2 * 32 + quad * 8]);
                const int kb_r = ks2 * 4 + quad;
#pragma unroll
                for (int nt = 0; nt < 8; ++nt) {
                    const int d = nt * 16 + l16;
                    bf16x8 bv = *(const bf16x8*)(Vt + d * 64 + ((kb_r ^ (d & 7)) << 3));
                    acc_o[nt] = MFMA16(ap, bv, acc_o[nt]);
                }
            }
        }

#pragma unroll
        for (int r = 0; r < 4; ++r) {
            float inv = 1.f / fmaxf(l_r[r], 1e-30f);
            size_t orow = (size_t)b * 2048 + q0 + wave * 16 + quad * 4 + r;
#pragma unroll
            for (int nt = 0; nt < 8; ++nt)
                O[orow * 2048 + h * 128 + nt * 16 + l16] = (bf16_t)(acc_o[nt][r] * inv);
        }
    }
}

// ---------------------------------------------------------------------------
// Launch. Tiers by ws_size:
//  >= 220 MB: all-gemm8 path (fused KV, split gate/up with silu epilogue)
//  >= 174 MB: round-2 path (gemm8 Q/O/down, gemm_bb K/V, gateup8)
//  else:      round-4 fallback (fp32 weights)
// Branch is on ws_size (constant across calls) -> graph-capture safe.
// ---------------------------------------------------------------------------
extern "C" void kernel_launch(void* const* d_in, const int* in_sizes, int n_in,
                              void* d_out, int out_size, void* d_ws, size_t ws_size,
                              hipStream_t stream)
{
    const float* x   = (const float*)d_in[0];
    const float* qw  = (const float*)d_in[2];
    const float* kw  = (const float*)d_in[3];
    const float* vw  = (const float*)d_in[4];
    const float* ow  = (const float*)d_in[5];
    const float* gw  = (const float*)d_in[6];
    const float* uw  = (const float*)d_in[7];
    const float* dw  = (const float*)d_in[8];
    const float* ln1 = (const float*)d_in[9];
    const float* ln2 = (const float*)d_in[10];
    float*  out = (float*)d_out;
    bf16_t* ws  = (bf16_t*)d_ws;

    dim3 blk(256);
    const size_t NEED1 = 87031808ull * 2;                    // 174 MB
    const size_t NEED2 = (87031808ull + 23068672ull) * 2;    // 220 MB

    if (ws_size >= NEED1) {
        // ---- shared workspace layout (bf16 weights + activations) ----
        bf16_t* wq = ws;                      // 4,194,304
        bf16_t* wk = ws + 4194304;            // 2,097,152  (wk||wv contiguous
        bf16_t* wv = ws + 6291456;            // 2,097,152   = [2048,2048] KV W)
        bf16_t* wo = ws + 8388608;            // 4,194,304
        bf16_t* wg = ws + 12582912;           // 11,534,336
        bf16_t* wu = ws + 24117248;           // 11,534,336
        bf16_t* wd = ws + 35651584;           // 11,534,336
        bf16_t* h1 = ws + 47185920;           // 8,388,608
        bf16_t* qb = ws + 55574528;           // 8,388,608 (later hb)
        bf16_t* kb = ws + 63963136;           // 4,194,304 (kv base; later gb)
        bf16_t* vb = ws + 68157440;           // 4,194,304
        bf16_t* ab = (bf16_t*)d_out;          // attn out scratch in d_out
        bf16_t* hb = qb;
        bf16_t* gb = kb;                      // 23,068,672 ends at 87,031,808
        bf16_t* gr = ws + 87031808;           // 23,068,672 (top tier only)

        wconv<<<2048, blk, 0, stream>>>(qw, wq, 4194304);
        wconv<<<1024, blk, 0, stream>>>(kw, wk, 2097152);
        wconv<<<1024, blk, 0, stream>>>(vw, wv, 2097152);
        wconv<<<2048, blk, 0, stream>>>(ow, wo, 4194304);
        wconv<<<5632, blk, 0, stream>>>(gw, wg, 11534336);
        wconv<<<5632, blk, 0, stream>>>(uw, wu, 11534336);
        wconv<<<5632, blk, 0, stream>>>(dw, wd, 11534336);

        rmsnorm_f32<<<4096, blk, 0, stream>>>(x, ln1, h1);

        if (ws_size >= NEED2) {
            // ---- top tier: all-gemm8 ----
            bf16_t* kv = kb;   // [4096, 2048] interleaved K|V per row
            gemm8<<<256, dim3(512), 0, stream>>>(h1, wq, nullptr, nullptr, qb, nullptr, 4096, 2048, 2048, 16, 0);
            gemm8<<<256, dim3(512), 0, stream>>>(h1, wk, nullptr, nullptr, kv, nullptr, 4096, 2048, 2048, 16, 0);
            attn_fwd<<<dim3(16, 32), blk, 0, stream>>>(qb, kv, kv + 1024, ab, 2048);
            gemm8<<<256, dim3(512), 0, stream>>>(ab, wo, x, nullptr, hb, nullptr, 4096, 2048, 2048, 16, 1);
            rmsnorm_bf16<<<4096, blk, 0, stream>>>(hb, ln2, h1);
            gemm8<<<704, dim3(512), 0, stream>>>(h1, wg, nullptr, nullptr, gr, nullptr, 4096, 5632, 2048, 44, 0);
            gemm8<<<704, dim3(512), 0, stream>>>(h1, wu, nullptr, gr, gb, nullptr, 4096, 5632, 2048, 44, 4);
            gemm8<<<256, dim3(512), 0, stream>>>(gb, wd, nullptr, hb, nullptr, out, 4096, 2048, 5632, 16, 2);
        } else {
            // ---- middle tier: round-2 path ----
            gemm8<<<256, dim3(512), 0, stream>>>(h1, wq, nullptr, nullptr, qb, nullptr, 4096, 2048, 2048, 16, 0);
            gemm_bb<<<dim3( 8, 32), blk, 0, stream>>>(h1, wk, nullptr, nullptr, kb, nullptr, 4096, 1024, 2048, 0);
            gemm_bb<<<dim3( 8, 32), blk, 0, stream>>>(h1, wv, nullptr, nullptr, vb, nullptr, 4096, 1024, 2048, 0);
            attn_fwd<<<dim3(16, 32), blk, 0, stream>>>(qb, kb, vb, ab, 1024);
            gemm8<<<256, dim3(512), 0, stream>>>(ab, wo, x, nullptr, hb, nullptr, 4096, 2048, 2048, 16, 1);
            rmsnorm_bf16<<<4096, blk, 0, stream>>>(hb, ln2, h1);
            gateup8<<<704, dim3(512), 0, stream>>>(h1, wg, wu, gb, 4096, 5632, 2048);
            gemm8<<<256, dim3(512), 0, stream>>>(gb, wd, nullptr, hb, nullptr, out, 4096, 2048, 5632, 16, 2);
        }
    } else {
        // ---- fallback: round-4 mixed path (78 MB) ----
        const size_t ME = 1ull << 20;
        bf16_t* h1 = ws;
        bf16_t* qb = ws + 8  * ME;
        bf16_t* kb = ws + 16 * ME;
        bf16_t* vb = ws + 20 * ME;
        bf16_t* ab = (bf16_t*)d_out;
        bf16_t* hb = ws + 8  * ME;
        bf16_t* gb = ws + 16 * ME;

        rmsnorm_f32<<<4096, blk, 0, stream>>>(x, ln1, h1);
        gemm_bt<<<dim3(16, 32), blk, 0, stream>>>(h1, qw, nullptr, nullptr, qb, nullptr, 4096, 2048, 2048, 0);
        gemm_bt<<<dim3( 8, 32), blk, 0, stream>>>(h1, kw, nullptr, nullptr, kb, nullptr, 4096, 1024, 2048, 0);
        gemm_bt<<<dim3( 8, 32), blk, 0, stream>>>(h1, vw, nullptr, nullptr, vb, nullptr, 4096, 1024, 2048, 0);
        attn_fwd<<<dim3(16, 32), blk, 0, stream>>>(qb, kb, vb, ab, 1024);
        gemm_bt<<<dim3(16, 32), blk, 0, stream>>>(ab, ow, x, nullptr, hb, nullptr, 4096, 2048, 2048, 1);
        rmsnorm_bf16<<<4096, blk, 0, stream>>>(hb, ln2, h1);
        gemm_gateup<<<dim3(44, 32), blk, 0, stream>>>(h1, gw, uw, gb, 4096, 5632, 2048);
        gemm_bt<<<dim3(16, 32), blk, 0, stream>>>(gb, dw, nullptr, hb, nullptr, out, 4096, 2048, 5632, 2);
    }
}

// Round 4
// 818.801 us; speedup vs baseline: 1.2949x; 1.2949x over previous
//
#include <hip/hip_runtime.h>
#include <stdint.h>

typedef __bf16 bf16_t;
typedef __bf16 bf16x8 __attribute__((ext_vector_type(8)));
typedef __bf16 bf16x4 __attribute__((ext_vector_type(4)));
typedef float  f32x4  __attribute__((ext_vector_type(4)));

#define MFMA16(a, b, c) __builtin_amdgcn_mfma_f32_16x16x32_bf16((a), (b), (c), 0, 0, 0)

// Async global->LDS 16B/lane. LDS dest is wave-uniform base + lane*16; our
// lds ptr is computed as base + lane*16, matching the HW contract (m97/m104).
__device__ __forceinline__ void load_lds16(const bf16_t* g, bf16_t* l)
{
    __builtin_amdgcn_global_load_lds(
        (const __attribute__((address_space(1))) uint32_t*)(uintptr_t)g,
        (__attribute__((address_space(3))) uint32_t*)(uint32_t)(uintptr_t)l,
        16, 0, 0);
}

// Stage 2x16B per thread into LDS with T2 inverse-swizzled global source.
// LDS linear slot u*16B holds global[row][ (x ^ ((row&7)<<3)) ] for x in the
// 8-elem group; readers apply the same XOR (involution, rule 21).
__device__ __forceinline__ void lds_stage2(const bf16_t* __restrict__ Gsrc,
                                           bf16_t* Ldst, int u0,
                                           int tid, int K, int k0)
{
#pragma unroll
    for (int l = 0; l < 2; ++l) {
        int u = u0 + l * 512 + tid;
        int row = u >> 3;
        int col = (((u & 7) ^ (row & 7)) << 3);
        load_lds16(Gsrc + (size_t)row * K + k0 + col, Ldst + u * 8);
    }
}

// ---------------------------------------------------------------------------
// Weight convert fp32 -> bf16, 8 elems/thread
// ---------------------------------------------------------------------------
__global__ __launch_bounds__(256)
void wconv(const float* __restrict__ X, bf16_t* __restrict__ Y, int n)
{
    int i = (blockIdx.x * 256 + threadIdx.x) * 8;
    if (i >= n) return;
    f32x4 a = *(const f32x4*)(X + i);
    f32x4 b = *(const f32x4*)(X + i + 4);
    bf16x8 y;
#pragma unroll
    for (int e = 0; e < 4; ++e) { y[e] = (bf16_t)a[e]; y[e + 4] = (bf16_t)b[e]; }
    *(bf16x8*)(Y + i) = y;
}

// ---------------------------------------------------------------------------
// RMSNorm (fp32 in -> bf16 out)
// ---------------------------------------------------------------------------
__global__ __launch_bounds__(256)
void rmsnorm_f32(const float* __restrict__ X, const float* __restrict__ Wt,
                 bf16_t* __restrict__ Y)
{
    __shared__ float red[4];
    const int tid = threadIdx.x;
    const size_t row = blockIdx.x;
    const float* x = X + row * 2048;

    f32x4 x0 = *(const f32x4*)(x + tid * 8);
    f32x4 x1 = *(const f32x4*)(x + tid * 8 + 4);
    float ss = 0.f;
#pragma unroll
    for (int e = 0; e < 4; ++e) ss += x0[e] * x0[e] + x1[e] * x1[e];
#pragma unroll
    for (int off = 32; off; off >>= 1) ss += __shfl_xor(ss, off, 64);
    if ((tid & 63) == 0) red[tid >> 6] = ss;
    __syncthreads();
    float tot = red[0] + red[1] + red[2] + red[3];
    float scale = rsqrtf(tot * (1.f / 2048.f) + 1e-6f);

    f32x4 w0 = *(const f32x4*)(Wt + tid * 8);
    f32x4 w1 = *(const f32x4*)(Wt + tid * 8 + 4);
    bf16x8 yv;
#pragma unroll
    for (int e = 0; e < 4; ++e) {
        yv[e]     = (bf16_t)(x0[e] * scale * w0[e]);
        yv[e + 4] = (bf16_t)(x1[e] * scale * w1[e]);
    }
    *(bf16x8*)(Y + row * 2048 + tid * 8) = yv;
}

// ---------------------------------------------------------------------------
// RMSNorm (bf16 in -> bf16 out), fp32 gamma
// ---------------------------------------------------------------------------
__global__ __launch_bounds__(256)
void rmsnorm_bf16(const bf16_t* __restrict__ X, const float* __restrict__ Wt,
                  bf16_t* __restrict__ Y)
{
    __shared__ float red[4];
    const int tid = threadIdx.x;
    const size_t row = blockIdx.x;

    bf16x8 xv = *(const bf16x8*)(X + row * 2048 + tid * 8);
    float xf[8];
    float ss = 0.f;
#pragma unroll
    for (int e = 0; e < 8; ++e) { xf[e] = (float)xv[e]; ss += xf[e] * xf[e]; }
#pragma unroll
    for (int off = 32; off; off >>= 1) ss += __shfl_xor(ss, off, 64);
    if ((tid & 63) == 0) red[tid >> 6] = ss;
    __syncthreads();
    float tot = red[0] + red[1] + red[2] + red[3];
    float scale = rsqrtf(tot * (1.f / 2048.f) + 1e-6f);

    f32x4 w0 = *(const f32x4*)(Wt + tid * 8);
    f32x4 w1 = *(const f32x4*)(Wt + tid * 8 + 4);
    bf16x8 yv;
#pragma unroll
    for (int e = 0; e < 4; ++e) {
        yv[e]     = (bf16_t)(xf[e] * scale * w0[e]);
        yv[e + 4] = (bf16_t)(xf[e + 4] * scale * w1[e]);
    }
    *(bf16x8*)(Y + row * 2048 + tid * 8) = yv;
}

// ---------------------------------------------------------------------------
// 8-phase GEMM (T1+T2+T3+T4+T5), tile 256x128, 8 waves as 4M x 2N
// (per-wave 64x64), double-buffered 96 KiB LDS, balanced 2 phases/K-tile
// (8 ds_reads -> 16 MFMA each), stage pairs at top/P0/P1, counted vmcnt(2).
// Grid = (M/256)*nbx blocks (must be %8==0); M assumed 4096 (16 M-panels).
// mode 0: Cb=acc | 1: Cb=acc+Rf(f32) | 2: Cf=acc+Rb(bf16)
// mode 5: split store (N=2048): cols 0..1023 -> Cb, 1024..2047 -> Cb2,
//         both with row stride 1024 (fused K|V projection).
// ---------------------------------------------------------------------------
__global__ __launch_bounds__(512, 2)
void gemm8(const bf16_t* __restrict__ A, const bf16_t* __restrict__ W,
           const float* __restrict__ Rf, const bf16_t* __restrict__ Rb,
           bf16_t* __restrict__ Cb, bf16_t* __restrict__ Cb2,
           float* __restrict__ Cf,
           int M, int N, int K, int nbx, int mode)
{
    __shared__ bf16_t As[2][256 * 64];   // 64 KiB
    __shared__ bf16_t Ws[2][128 * 64];   // 32 KiB

    const int tid  = threadIdx.x;
    const int lane = tid & 63, wave = tid >> 6;
    const int quad = lane >> 4, l16 = lane & 15;
    const int wr = wave >> 1, wc = wave & 1;   // 4M x 2N wave grid

    // T1: bijective XCD swizzle (requires nwg % 8 == 0), W-panel-resident
    // ordering: consecutive swz share bxn -> W panel stays in the XCD's L2
    // across 16 M-blocks; A panels stream from L3 (shared by all XCDs).
    const int lid = (int)blockIdx.x;
    const int nwg = (M >> 8) * nbx;
    const int q   = nwg >> 3;
    const int swz = (lid & 7) * q + (lid >> 3);
    const int bxn = swz >> 4;                      // 0..nbx-1
    const int bym = swz & 15;                      // 0..15
    const int m0 = bym * 256, n0 = bxn * 128;

    const bf16_t* Ab = A + (size_t)m0 * K;
    const bf16_t* Wb = W + (size_t)n0 * K;

    const int xsw  = (l16 & 7) << 3;               // T2 read-side XOR (elems)
    const int aoff = (wr * 64 + l16) * 64;
    const int boff = (wc * 64 + l16) * 64;

    f32x4 acc[4][4] = {};

    // prologue: stage tile 0 fully (6 loads/thread)
    lds_stage2(Ab, As[0], 0,    tid, K, 0);
    lds_stage2(Ab, As[0], 1024, tid, K, 0);
    lds_stage2(Wb, Ws[0], 0,    tid, K, 0);

    const int NT = K >> 6;
    for (int t = 0; t < NT; ++t) {
        const int b  = t & 1;
        const int kn = (t + 1) << 6;
        const bool pf = (t + 1 < NT);
        bf16_t* An = As[1 - b];
        bf16_t* Wn = Ws[1 - b];

        if (pf) {
            lds_stage2(Ab, An, 0, tid, K, kn);
            // T4: drain tile t's 6 loads; the 2 just issued stay in flight.
            asm volatile("s_waitcnt vmcnt(2)" ::: "memory");
        } else {
            asm volatile("s_waitcnt vmcnt(0)" ::: "memory");
        }
        __builtin_amdgcn_s_barrier();   // tile t visible to ALL waves

        const bf16_t* Asb = As[b];
        const bf16_t* Wsb = Ws[b];

#pragma unroll
        for (int ks = 0; ks < 2; ++ks) {
            const int kxo = (ks * 32 + quad * 8) ^ xsw;
            bf16x8 af[4], bf_[4];
#pragma unroll
            for (int i = 0; i < 4; ++i)
                af[i] = *(const bf16x8*)(Asb + aoff + i * 1024 + kxo);
#pragma unroll
            for (int j = 0; j < 4; ++j)
                bf_[j] = *(const bf16x8*)(Wsb + boff + j * 1024 + kxo);
            if (pf) {
                if (ks == 0) lds_stage2(Ab, An, 1024, tid, K, kn);
                else         lds_stage2(Wb, Wn, 0,    tid, K, kn);
            }
            __builtin_amdgcn_s_barrier();
            __builtin_amdgcn_s_setprio(1);
#pragma unroll
            for (int i = 0; i < 4; ++i)
#pragma unroll
                for (int j = 0; j < 4; ++j)
                    acc[i][j] = MFMA16(af[i], bf_[j], acc[i][j]);
            __builtin_amdgcn_s_setprio(0);
            __builtin_amdgcn_s_barrier();
        }
    }

    bf16_t* dst5 = (n0 < 1024) ? Cb : Cb2;   // mode 5 split base (block-uniform)

#pragma unroll
    for (int i = 0; i < 4; ++i)
#pragma unroll
        for (int j = 0; j < 4; ++j)
#pragma unroll
            for (int r = 0; r < 4; ++r) {
                size_t row = (size_t)(m0 + wr * 64 + i * 16 + quad * 4 + r);
                size_t col = (size_t)(n0 + wc * 64 + j * 16 + l16);
                float v = acc[i][j][r];
                if (mode == 1) v += Rf[row * (size_t)N + col];
                if (mode == 2)
                    Cf[row * (size_t)N + col] = v + (float)Rb[row * (size_t)N + col];
                else if (mode == 5)
                    dst5[row * 1024 + (col & 1023)] = (bf16_t)v;
                else
                    Cb[row * (size_t)N + col] = (bf16_t)v;
            }
}

// ---------------------------------------------------------------------------
// Fused gate+up SwiGLU GEMM (round-2 version, measured 217 us).
// ---------------------------------------------------------------------------
__global__ __launch_bounds__(512, 2)
void gateup8(const bf16_t* __restrict__ A, const bf16_t* __restrict__ G,
             const bf16_t* __restrict__ U, bf16_t* __restrict__ C,
             int M, int N, int K)
{
    __shared__ bf16_t As[2][256 * 64];   // 64 KiB
    __shared__ bf16_t Gs[2][128 * 64];   // 32 KiB
    __shared__ bf16_t Us[2][128 * 64];   // 32 KiB

    const int tid  = threadIdx.x;
    const int lane = tid & 63;
    const int wave = tid >> 6;
    const int quad = lane >> 4, l16 = lane & 15;
    const int wr = wave >> 2, wc = wave & 3;      // 2M x 4N wave grid

    const int lid = (int)blockIdx.x;
    const int nwg = (M >> 8) * (N >> 7);          // 16 * 44 = 704
    const int cpx = nwg >> 3;                     // 88
    const int swz = (lid & 7) * cpx + (lid >> 3);
    const int bxn = swz >> 4;                     // N-block (44)
    const int bym = swz & 15;                     // M-block (16)
    const int m0 = bym * 256, n0 = bxn * 128;

    const bf16_t* Ab = A + (size_t)m0 * K;
    const bf16_t* Gb = G + (size_t)n0 * K;
    const bf16_t* Ub = U + (size_t)n0 * K;

    const int xsw  = (l16 & 7) << 3;              // T2 read-side XOR (elems)
    const int aoff = (wr * 128 + l16) * 64;
    const int boff = (wc * 32 + l16) * 64;

    f32x4 accg[8][2] = {};
    f32x4 accu[8][2] = {};

    lds_stage2(Ab, As[0], 0,    tid, K, 0);
    lds_stage2(Ab, As[0], 1024, tid, K, 0);
    lds_stage2(Gb, Gs[0], 0,    tid, K, 0);
    lds_stage2(Ub, Us[0], 0,    tid, K, 0);

    const int NT = K >> 6;                        // 32 K-tiles
    for (int t = 0; t < NT; ++t) {
        const int b  = t & 1;
        const int kn = (t + 1) << 6;
        const bool pf = (t + 1 < NT);
        bf16_t* An = As[1 - b];
        bf16_t* Gn = Gs[1 - b];
        bf16_t* Un = Us[1 - b];

        if (pf) {
            lds_stage2(Ab, An, 0, tid, K, kn);
            asm volatile("s_waitcnt vmcnt(2)" ::: "memory");
        } else {
            asm volatile("s_waitcnt vmcnt(0)" ::: "memory");
        }
        __builtin_amdgcn_s_barrier();

        const bf16_t* Asb = As[b];
        const bf16_t* Gsb = Gs[b];
        const bf16_t* Usb = Us[b];

        bf16x8 af[4], bg[2], bu[2];

        // ---- P0: ks=0, A rows lo ----
        {
            const int kxo = (quad * 8) ^ xsw;
#pragma unroll
            for (int i = 0; i < 4; ++i)
                af[i] = *(const bf16x8*)(Asb + aoff + i * 1024 + kxo);
#pragma unroll
            for (int j = 0; j < 2; ++j) {
                bg[j] = *(const bf16x8*)(Gsb + boff + j * 1024 + kxo);
                bu[j] = *(const bf16x8*)(Usb + boff + j * 1024 + kxo);
            }
        }
        if (pf) lds_stage2(Ab, An, 1024, tid, K, kn);
        __builtin_amdgcn_s_barrier();
        __builtin_amdgcn_s_setprio(1);
#pragma unroll
        for (int i = 0; i < 4; ++i)
#pragma unroll
            for (int j = 0; j < 2; ++j) {
                accg[i][j] = MFMA16(af[i], bg[j], accg[i][j]);
                accu[i][j] = MFMA16(af[i], bu[j], accu[i][j]);
            }
        __builtin_amdgcn_s_setprio(0);
        __builtin_amdgcn_s_barrier();

        // ---- P1: ks=0, A rows hi ----
        {
            const int kxo = (quad * 8) ^ xsw;
#pragma unroll
            for (int i = 0; i < 4; ++i)
                af[i] = *(const bf16x8*)(Asb + aoff + (i + 4) * 1024 + kxo);
        }
        if (pf) lds_stage2(Gb, Gn, 0, tid, K, kn);
        __builtin_amdgcn_s_barrier();
        __builtin_amdgcn_s_setprio(1);
#pragma unroll
        for (int i = 0; i < 4; ++i)
#pragma unroll
            for (int j = 0; j < 2; ++j) {
                accg[i + 4][j] = MFMA16(af[i], bg[j], accg[i + 4][j]);
                accu[i + 4][j] = MFMA16(af[i], bu[j], accu[i + 4][j]);
            }
        __builtin_amdgcn_s_setprio(0);
        __builtin_amdgcn_s_barrier();

        // ---- P2: ks=1, A rows lo ----
        {
            const int kxo = (32 + quad * 8) ^ xsw;
#pragma unroll
            for (int i = 0; i < 4; ++i)
                af[i] = *(const bf16x8*)(Asb + aoff + i * 1024 + kxo);
#pragma unroll
            for (int j = 0; j < 2; ++j) {
                bg[j] = *(const bf16x8*)(Gsb + boff + j * 1024 + kxo);
                bu[j] = *(const bf16x8*)(Usb + boff + j * 1024 + kxo);
            }
        }
        if (pf) lds_stage2(Ub, Un, 0, tid, K, kn);
        __builtin_amdgcn_s_barrier();
        __builtin_amdgcn_s_setprio(1);
#pragma unroll
        for (int i = 0; i < 4; ++i)
#pragma unroll
            for (int j = 0; j < 2; ++j) {
                accg[i][j] = MFMA16(af[i], bg[j], accg[i][j]);
                accu[i][j] = MFMA16(af[i], bu[j], accu[i][j]);
            }
        __builtin_amdgcn_s_setprio(0);
        __builtin_amdgcn_s_barrier();

        // ---- P3: ks=1, A rows hi ----
        {
            const int kxo = (32 + quad * 8) ^ xsw;
#pragma unroll
            for (int i = 0; i < 4; ++i)
                af[i] = *(const bf16x8*)(Asb + aoff + (i + 4) * 1024 + kxo);
        }
        __builtin_amdgcn_s_barrier();
        __builtin_amdgcn_s_setprio(1);
#pragma unroll
        for (int i = 0; i < 4; ++i)
#pragma unroll
            for (int j = 0; j < 2; ++j) {
                accg[i + 4][j] = MFMA16(af[i], bg[j], accg[i + 4][j]);
                accu[i + 4][j] = MFMA16(af[i], bu[j], accu[i + 4][j]);
            }
        __builtin_amdgcn_s_setprio(0);
        __builtin_amdgcn_s_barrier();
    }

#pragma unroll
    for (int i = 0; i < 8; ++i)
#pragma unroll
        for (int j = 0; j < 2; ++j)
#pragma unroll
            for (int r = 0; r < 4; ++r) {
                size_t row = (size_t)(m0 + wr * 128 + i * 16 + quad * 4 + r);
                size_t col = (size_t)(n0 + wc * 32 + j * 16 + l16);
                float g = accg[i][j][r];
                float u = accu[i][j][r];
                float sig = 1.f / (1.f + __expf(fminf(-g, 80.f)));
                C[row * (size_t)N + col] = (bf16_t)(g * sig * u);
            }
}

// ---------------------------------------------------------------------------
// FALLBACK GEMM (round-4 path, fp32 weights staged in registers)
// ---------------------------------------------------------------------------
__global__ __launch_bounds__(256, 2)
void gemm_bt(const bf16_t* __restrict__ A, const float* __restrict__ W,
             const float* __restrict__ Rf, const bf16_t* __restrict__ Rb,
             bf16_t* __restrict__ Cb, float* __restrict__ Cf,
             int M, int N, int K, int mode)
{
    __shared__ bf16_t As[128 * 64];
    __shared__ bf16_t Ws[128 * 64];

    const int tid  = threadIdx.x;
    const int lane = tid & 63, wave = tid >> 6;
    const int quad = lane >> 4, l16 = lane & 15;
    const int m0 = blockIdx.y * 128, n0 = blockIdx.x * 128;
    const int wm = (wave >> 1) * 64, wn = (wave & 1) * 64;

    f32x4 acc[4][4] = {};

    for (int k0 = 0; k0 < K; k0 += 64) {
        bf16x8 ra[4];
        bf16x4 rw[8];
#pragma unroll
        for (int i = 0; i < 4; ++i) {
            int u = i * 256 + tid;
            int r = u >> 3, c = (u & 7) << 3;
            ra[i] = *(const bf16x8*)(A + (size_t)(m0 + r) * K + k0 + c);
        }
#pragma unroll
        for (int i = 0; i < 8; ++i) {
            int u = i * 256 + tid;
            int r = u >> 4, c = (u & 15) << 2;
            f32x4 w4 = *(const f32x4*)(W + (size_t)(n0 + r) * K + k0 + c);
#pragma unroll
            for (int e = 0; e < 4; ++e) rw[i][e] = (bf16_t)w4[e];
        }
        __syncthreads();
#pragma unroll
        for (int i = 0; i < 4; ++i)
            *(bf16x8*)(As + (i * 256 + tid) * 8) = ra[i];
#pragma unroll
        for (int i = 0; i < 8; ++i)
            *(bf16x4*)(Ws + (i * 256 + tid) * 4) = rw[i];
        __syncthreads();

#pragma unroll
        for (int ks = 0; ks < 64; ks += 32) {
            bf16x8 af[4], bfr[4];
#pragma unroll
            for (int i = 0; i < 4; ++i)
                af[i] = *(const bf16x8*)(As + (wm + i * 16 + l16) * 64 + ks + quad * 8);
#pragma unroll
            for (int j = 0; j < 4; ++j)
                bfr[j] = *(const bf16x8*)(Ws + (wn + j * 16 + l16) * 64 + ks + quad * 8);
#pragma unroll
            for (int i = 0; i < 4; ++i)
#pragma unroll
                for (int j = 0; j < 4; ++j)
                    acc[i][j] = MFMA16(af[i], bfr[j], acc[i][j]);
        }
    }

#pragma unroll
    for (int i = 0; i < 4; ++i)
#pragma unroll
        for (int j = 0; j < 4; ++j)
#pragma unroll
            for (int r = 0; r < 4; ++r) {
                size_t row = (size_t)(m0 + wm + i * 16 + quad * 4 + r);
                size_t col = (size_t)(n0 + wn + j * 16 + l16);
                float v = acc[i][j][r];
                if (mode == 1) v += Rf[row * (size_t)N + col];
                if (mode == 2)
                    Cf[row * (size_t)N + col] = v + (float)Rb[row * (size_t)N + col];
                else
                    Cb[row * (size_t)N + col] = (bf16_t)v;
            }
}

// ---------------------------------------------------------------------------
// FALLBACK fused gate+up (round-4 path, fp32 weights)
// ---------------------------------------------------------------------------
__global__ __launch_bounds__(256, 2)
void gemm_gateup(const bf16_t* __restrict__ A, const float* __restrict__ G,
                 const float* __restrict__ U, bf16_t* __restrict__ C,
                 int M, int N, int K)
{
    __shared__ bf16_t As[128 * 64];
    __shared__ bf16_t Gs[128 * 64];
    __shared__ bf16_t Us[128 * 64];

    const int tid  = threadIdx.x;
    const int lane = tid & 63, wave = tid >> 6;
    const int quad = lane >> 4, l16 = lane & 15;
    const int m0 = blockIdx.y * 128, n0 = blockIdx.x * 128;
    const int wm = (wave >> 1) * 64, wn = (wave & 1) * 64;

    f32x4 accg[4][4] = {};
    f32x4 accu[4][4] = {};

    for (int k0 = 0; k0 < K; k0 += 64) {
        bf16x8 ra[4];
        bf16x4 rg[8], ru[8];
#pragma unroll
        for (int i = 0; i < 4; ++i) {
            int u = i * 256 + tid;
            int r = u >> 3, c = (u & 7) << 3;
            ra[i] = *(const bf16x8*)(A + (size_t)(m0 + r) * K + k0 + c);
        }
#pragma unroll
        for (int i = 0; i < 8; ++i) {
            int u = i * 256 + tid;
            int r = u >> 4, c = (u & 15) << 2;
            f32x4 g4 = *(const f32x4*)(G + (size_t)(n0 + r) * K + k0 + c);
            f32x4 u4 = *(const f32x4*)(U + (size_t)(n0 + r) * K + k0 + c);
#pragma unroll
            for (int e = 0; e < 4; ++e) { rg[i][e] = (bf16_t)g4[e]; ru[i][e] = (bf16_t)u4[e]; }
        }
        __syncthreads();
#pragma unroll
        for (int i = 0; i < 4; ++i)
            *(bf16x8*)(As + (i * 256 + tid) * 8) = ra[i];
#pragma unroll
        for (int i = 0; i < 8; ++i) {
            *(bf16x4*)(Gs + (i * 256 + tid) * 4) = rg[i];
            *(bf16x4*)(Us + (i * 256 + tid) * 4) = ru[i];
        }
        __syncthreads();

#pragma unroll
        for (int ks = 0; ks < 64; ks += 32) {
            bf16x8 af[4], bg[4], bu[4];
#pragma unroll
            for (int i = 0; i < 4; ++i)
                af[i] = *(const bf16x8*)(As + (wm + i * 16 + l16) * 64 + ks + quad * 8);
#pragma unroll
            for (int j = 0; j < 4; ++j) {
                bg[j] = *(const bf16x8*)(Gs + (wn + j * 16 + l16) * 64 + ks + quad * 8);
                bu[j] = *(const bf16x8*)(Us + (wn + j * 16 + l16) * 64 + ks + quad * 8);
            }
#pragma unroll
            for (int i = 0; i < 4; ++i)
#pragma unroll
                for (int j = 0; j < 4; ++j) {
                    accg[i][j] = MFMA16(af[i], bg[j], accg[i][j]);
                    accu[i][j] = MFMA16(af[i], bu[j], accu[i][j]);
                }
        }
    }

#pragma unroll
    for (int i = 0; i < 4; ++i)
#pragma unroll
        for (int j = 0; j < 4; ++j)
#pragma unroll
            for (int r = 0; r < 4; ++r) {
                size_t row = (size_t)(m0 + wm + i * 16 + quad * 4 + r);
                size_t col = (size_t)(n0 + wn + j * 16 + l16);
                float g = accg[i][j][r];
                float u = accu[i][j][r];
                float sig = 1.f / (1.f + __expf(fminf(-g, 80.f)));
                C[row * (size_t)N + col] = (bf16_t)(g * sig * u);
            }
}

// ---------------------------------------------------------------------------
// Flash attention fwd, round-4 rewrite:
//  - Ks XOR-swizzled (col ^= (row&7)<<3): QK ds_read_b128 conflict-free
//    (was 16-way at row stride 256B).
//  - Double-buffered K/V with early-issue register prefetch (T14): tile t+1's
//    global loads issue before tile t's compute; ds_writes land after the
//    single end-of-iter barrier. HBM latency hides under QK+softmax+PV.
//  - One __syncthreads per tile (was 3).
// kvs = row stride of K/V buffers (1024 = separate contiguous buffers).
// ---------------------------------------------------------------------------
__global__ __launch_bounds__(256, 2)
void attn_fwd(const bf16_t* __restrict__ Q, const bf16_t* __restrict__ Kg,
              const bf16_t* __restrict__ Vg, bf16_t* __restrict__ O, int kvs)
{
    __shared__ bf16_t Ks[2][64 * 128];   // col XOR-swizzled by (row&7)<<3
    __shared__ bf16_t Vt[2][128 * 64];   // Vt[d][kb], slot = kb^(d&7)
    __shared__ bf16_t Pl[4][16 * 72];    // padded stride 72

    const int tid  = threadIdx.x;
    const int lane = tid & 63, wave = tid >> 6;
    const int quad = lane >> 4, l16 = lane & 15;
    const int bh = blockIdx.y, b = bh >> 4, h = bh & 15;

    const bf16_t* Qh = Q  + (size_t)b * 2048 * 2048 + (size_t)h * 128;
    const bf16_t* Kh = Kg + (size_t)b * 2048 * kvs + (size_t)(h >> 1) * 128;
    const bf16_t* Vh = Vg + (size_t)b * 2048 * kvs + (size_t)(h >> 1) * 128;

    const float scale = 0.08838834764831845f;   // 1/sqrt(128)

    // per-thread staging decomposition
    const int krow = tid >> 4;            // K row within 16-row group
    const int kcol = (tid & 15) << 3;     // K col (8-elem granule)
    const int vd   = tid & 127;           // V transpose: d
    const int vkb  = tid >> 7;            // V transpose: kb base (+2*it)

#pragma unroll 1
    for (int pass = 0; pass < 2; ++pass) {
        const int qt = pass ? (31 - (int)blockIdx.x) : (int)blockIdx.x;
        const int q0 = qt * 64;

        bf16x8 aq[4];
#pragma unroll
        for (int ks = 0; ks < 4; ++ks)
            aq[ks] = *(const bf16x8*)(Qh + (size_t)(q0 + wave * 16 + l16) * 2048 + ks * 32 + quad * 8);

        float m_r[4] = { -30000.f, -30000.f, -30000.f, -30000.f };
        float l_r[4] = { 0.f, 0.f, 0.f, 0.f };
        f32x4 acc_o[8] = {};

        const int ntiles = qt + 1;

        bf16x8 rk[4], rv[4];
        // ---- prologue: stage tile 0 into buf 0 ----
#pragma unroll
        for (int i = 0; i < 4; ++i)
            rk[i] = *(const bf16x8*)(Kh + (size_t)(i * 16 + krow) * kvs + kcol);
#pragma unroll
        for (int it = 0; it < 4; ++it)
#pragma unroll
            for (int j = 0; j < 8; ++j)
                rv[it][j] = Vh[(size_t)((vkb + 2 * it) * 8 + j) * kvs + vd];
#pragma unroll
        for (int i = 0; i < 4; ++i) {
            int row = i * 16 + krow;
            *(bf16x8*)(&Ks[0][row * 128 + (kcol ^ ((row & 7) << 3))]) = rk[i];
        }
#pragma unroll
        for (int it = 0; it < 4; ++it) {
            int kb = vkb + 2 * it;
            *(bf16x8*)(&Vt[0][vd * 64 + ((kb ^ (vd & 7)) << 3)]) = rv[it];
        }
        __syncthreads();

        for (int t = 0; t < ntiles; ++t) {
            const int bb = t & 1;
            const bool pf = (t + 1 < ntiles);
            const int kv0 = t * 64;
            const int kvn = kv0 + 64;

            if (pf) {   // early-issue next tile's global loads (regs)
#pragma unroll
                for (int i = 0; i < 4; ++i)
                    rk[i] = *(const bf16x8*)(Kh + (size_t)(kvn + i * 16 + krow) * kvs + kcol);
#pragma unroll
                for (int it = 0; it < 4; ++it)
#pragma unroll
                    for (int j = 0; j < 8; ++j)
                        rv[it][j] = Vh[(size_t)(kvn + (vkb + 2 * it) * 8 + j) * kvs + vd];
            }

            // ---- QK^T (swizzled Ks reads, conflict-free) ----
            f32x4 accs[4] = {};
#pragma unroll
            for (int ks = 0; ks < 4; ++ks)
#pragma unroll
                for (int j = 0; j < 4; ++j) {
                    const int row = j * 16 + l16;
                    bf16x8 bk = *(const bf16x8*)(&Ks[bb][row * 128 + ((ks * 32 + quad * 8) ^ ((row & 7) << 3))]);
                    accs[j] = MFMA16(aq[ks], bk, accs[j]);
                }

            // ---- online softmax ----
#pragma unroll
            for (int r = 0; r < 4; ++r) {
                const int qrow = q0 + wave * 16 + quad * 4 + r;
                float s[4];
                float mx = -30000.f;
#pragma unroll
                for (int j = 0; j < 4; ++j) {
                    s[j] = accs[j][r] * scale;
                    if (kv0 + j * 16 + l16 > qrow) s[j] = -30000.f;
                    mx = fmaxf(mx, s[j]);
                }
                mx = fmaxf(mx, __shfl_xor(mx, 1, 64));
                mx = fmaxf(mx, __shfl_xor(mx, 2, 64));
                mx = fmaxf(mx, __shfl_xor(mx, 4, 64));
                mx = fmaxf(mx, __shfl_xor(mx, 8, 64));
                float mnew  = fmaxf(m_r[r], mx);
                float alpha = __expf(fmaxf(m_r[r] - mnew, -80.f));
                float rs = 0.f;
#pragma unroll
                for (int j = 0; j < 4; ++j) {
                    float p = __expf(fmaxf(s[j] - mnew, -80.f));
                    rs += p;
                    Pl[wave][(quad * 4 + r) * 72 + j * 16 + l16] = (bf16_t)p;
                }
                rs += __shfl_xor(rs, 1, 64);
                rs += __shfl_xor(rs, 2, 64);
                rs += __shfl_xor(rs, 4, 64);
                rs += __shfl_xor(rs, 8, 64);
                l_r[r] = l_r[r] * alpha + rs;
                m_r[r] = mnew;
#pragma unroll
                for (int nt = 0; nt < 8; ++nt) acc_o[nt][r] *= alpha;
            }

            // ---- PV (Pl is per-wave; compiler orders via lgkmcnt) ----
#pragma unroll
            for (int ks2 = 0; ks2 < 2; ++ks2) {
                bf16x8 ap = *(const bf16x8*)(&Pl[wave][l16 * 72 + ks2 * 32 + quad * 8]);
                const int kb_r = ks2 * 4 + quad;
#pragma unroll
                for (int nt = 0; nt < 8; ++nt) {
                    const int d = nt * 16 + l16;
                    bf16x8 bv = *(const bf16x8*)(&Vt[bb][d * 64 + ((kb_r ^ (d & 7)) << 3)]);
                    acc_o[nt] = MFMA16(ap, bv, acc_o[nt]);
                }
            }

            // ---- write prefetched tile into the other buffer ----
            if (pf) {
#pragma unroll
                for (int i = 0; i < 4; ++i) {
                    int row = i * 16 + krow;
                    *(bf16x8*)(&Ks[1 - bb][row * 128 + (kcol ^ ((row & 7) << 3))]) = rk[i];
                }
#pragma unroll
                for (int it = 0; it < 4; ++it) {
                    int kb = vkb + 2 * it;
                    *(bf16x8*)(&Vt[1 - bb][vd * 64 + ((kb ^ (vd & 7)) << 3)]) = rv[it];
                }
            }
            __syncthreads();   // buf[1-bb] writes visible; joint advance
        }

#pragma unroll
        for (int r = 0; r < 4; ++r) {
            float inv = 1.f / fmaxf(l_r[r], 1e-30f);
            size_t orow = (size_t)b * 2048 + q0 + wave * 16 + quad * 4 + r;
#pragma unroll
            for (int nt = 0; nt < 8; ++nt)
                O[orow * 2048 + h * 128 + nt * 16 + l16] = (bf16_t)(acc_o[nt][r] * inv);
        }
    }
}

// ---------------------------------------------------------------------------
// Launch. Fast path (ws >= 174 MB): bf16 weights; gemm8 for Q/KV/O/down
// (KV fused with split store -> contiguous kb/vb), gateup8 for MLP,
// rewritten attn. Fallback: round-4 mixed path.
// Branch is on ws_size (constant across calls) -> graph-capture safe.
// ---------------------------------------------------------------------------
extern "C" void kernel_launch(void* const* d_in, const int* in_sizes, int n_in,
                              void* d_out, int out_size, void* d_ws, size_t ws_size,
                              hipStream_t stream)
{
    const float* x   = (const float*)d_in[0];
    const float* qw  = (const float*)d_in[2];
    const float* kw  = (const float*)d_in[3];
    const float* vw  = (const float*)d_in[4];
    const float* ow  = (const float*)d_in[5];
    const float* gw  = (const float*)d_in[6];
    const float* uw  = (const float*)d_in[7];
    const float* dw  = (const float*)d_in[8];
    const float* ln1 = (const float*)d_in[9];
    const float* ln2 = (const float*)d_in[10];
    float*  out = (float*)d_out;
    bf16_t* ws  = (bf16_t*)d_ws;

    dim3 blk(256);
    const size_t NEED = 87031808ull * 2;   // 174 MB

    if (ws_size >= NEED) {
        // ---- fast path: bf16 weights + async-staged GEMMs ----
        bf16_t* wq = ws;                      // 4,194,304
        bf16_t* wk = ws + 4194304;            // 2,097,152  (wk||wv contiguous
        bf16_t* wv = ws + 6291456;            // 2,097,152   = [2048,2048] KV W)
        bf16_t* wo = ws + 8388608;            // 4,194,304
        bf16_t* wg = ws + 12582912;           // 11,534,336
        bf16_t* wu = ws + 24117248;           // 11,534,336
        bf16_t* wd = ws + 35651584;           // 11,534,336
        bf16_t* h1 = ws + 47185920;           // 8,388,608
        bf16_t* qb = ws + 55574528;           // 8,388,608 (later hb)
        bf16_t* kb = ws + 63963136;           // 4,194,304 (later gb)
        bf16_t* vb = ws + 68157440;           // 4,194,304
        bf16_t* ab = (bf16_t*)d_out;          // attn out scratch in d_out
        bf16_t* hb = qb;
        bf16_t* gb = kb;                      // 23,068,672 ends at 87,031,808

        wconv<<<2048, blk, 0, stream>>>(qw, wq, 4194304);
        wconv<<<1024, blk, 0, stream>>>(kw, wk, 2097152);
        wconv<<<1024, blk, 0, stream>>>(vw, wv, 2097152);
        wconv<<<2048, blk, 0, stream>>>(ow, wo, 4194304);
        wconv<<<5632, blk, 0, stream>>>(gw, wg, 11534336);
        wconv<<<5632, blk, 0, stream>>>(uw, wu, 11534336);
        wconv<<<5632, blk, 0, stream>>>(dw, wd, 11534336);

        rmsnorm_f32<<<4096, blk, 0, stream>>>(x, ln1, h1);
        gemm8<<<256, dim3(512), 0, stream>>>(h1, wq, nullptr, nullptr, qb, nullptr, nullptr, 4096, 2048, 2048, 16, 0);
        gemm8<<<256, dim3(512), 0, stream>>>(h1, wk, nullptr, nullptr, kb, vb, nullptr, 4096, 2048, 2048, 16, 5);
        attn_fwd<<<dim3(16, 32), blk, 0, stream>>>(qb, kb, vb, ab, 1024);
        gemm8<<<256, dim3(512), 0, stream>>>(ab, wo, x, nullptr, hb, nullptr, nullptr, 4096, 2048, 2048, 16, 1);
        rmsnorm_bf16<<<4096, blk, 0, stream>>>(hb, ln2, h1);
        gateup8<<<704, dim3(512), 0, stream>>>(h1, wg, wu, gb, 4096, 5632, 2048);
        gemm8<<<256, dim3(512), 0, stream>>>(gb, wd, nullptr, hb, nullptr, nullptr, out, 4096, 2048, 5632, 16, 2);
    } else {
        // ---- fallback: round-4 mixed path (78 MB) ----
        const size_t ME = 1ull << 20;
        bf16_t* h1 = ws;
        bf16_t* qb = ws + 8  * ME;
        bf16_t* kb = ws + 16 * ME;
        bf16_t* vb = ws + 20 * ME;
        bf16_t* ab = (bf16_t*)d_out;
        bf16_t* hb = ws + 8  * ME;
        bf16_t* gb = ws + 16 * ME;

        rmsnorm_f32<<<4096, blk, 0, stream>>>(x, ln1, h1);
        gemm_bt<<<dim3(16, 32), blk, 0, stream>>>(h1, qw, nullptr, nullptr, qb, nullptr, 4096, 2048, 2048, 0);
        gemm_bt<<<dim3( 8, 32), blk, 0, stream>>>(h1, kw, nullptr, nullptr, kb, nullptr, 4096, 1024, 2048, 0);
        gemm_bt<<<dim3( 8, 32), blk, 0, stream>>>(h1, vw, nullptr, nullptr, vb, nullptr, 4096, 1024, 2048, 0);
        attn_fwd<<<dim3(16, 32), blk, 0, stream>>>(qb, kb, vb, ab, 1024);
        gemm_bt<<<dim3(16, 32), blk, 0, stream>>>(ab, ow, x, nullptr, hb, nullptr, 4096, 2048, 2048, 1);
        rmsnorm_bf16<<<4096, blk, 0, stream>>>(hb, ln2, h1);
        gemm_gateup<<<dim3(44, 32), blk, 0, stream>>>(h1, gw, uw, gb, 4096, 5632, 2048);
        gemm_bt<<<dim3(16, 32), blk, 0, stream>>>(gb, dw, nullptr, hb, nullptr, out, 4096, 2048, 5632, 2);
    }
}

// Round 5
// 787.362 us; speedup vs baseline: 1.3467x; 1.0399x over previous
//
#include <hip/hip_runtime.h>
#include <stdint.h>

typedef __bf16 bf16_t;
typedef __bf16 bf16x8 __attribute__((ext_vector_type(8)));
typedef __bf16 bf16x4 __attribute__((ext_vector_type(4)));
typedef float  f32x4  __attribute__((ext_vector_type(4)));

#define MFMA16(a, b, c) __builtin_amdgcn_mfma_f32_16x16x32_bf16((a), (b), (c), 0, 0, 0)

// Async global->LDS 16B/lane. LDS dest is wave-uniform base + lane*16; our
// lds ptr is computed as base + lane*16, matching the HW contract (m97/m104).
__device__ __forceinline__ void load_lds16(const bf16_t* g, bf16_t* l)
{
    __builtin_amdgcn_global_load_lds(
        (const __attribute__((address_space(1))) uint32_t*)(uintptr_t)g,
        (__attribute__((address_space(3))) uint32_t*)(uint32_t)(uintptr_t)l,
        16, 0, 0);
}

// Stage 2x16B per thread into LDS with T2 inverse-swizzled global source.
// LDS linear slot u*16B holds global[row][ (x ^ ((row&7)<<3)) ] for x in the
// 8-elem group; readers apply the same XOR (involution, rule 21).
__device__ __forceinline__ void lds_stage2(const bf16_t* __restrict__ Gsrc,
                                           bf16_t* Ldst, int u0,
                                           int tid, int K, int k0)
{
#pragma unroll
    for (int l = 0; l < 2; ++l) {
        int u = u0 + l * 512 + tid;
        int row = u >> 3;
        int col = (((u & 7) ^ (row & 7)) << 3);
        load_lds16(Gsrc + (size_t)row * K + k0 + col, Ldst + u * 8);
    }
}

// ---------------------------------------------------------------------------
// All 7 weight conversions fp32 -> bf16 in ONE dispatch (segment by blockIdx).
// Segment block counts: q 2048 | k 1024 | v 1024 | o 2048 | g 5632 | u 5632
// | d 5632  (each block = 256 thr x 8 elems = 2048 elems; all sizes divide).
// ---------------------------------------------------------------------------
__global__ __launch_bounds__(256)
void wconv_all(const float* __restrict__ qw, const float* __restrict__ kw,
               const float* __restrict__ vw, const float* __restrict__ ow,
               const float* __restrict__ gw, const float* __restrict__ uw,
               const float* __restrict__ dw, bf16_t* __restrict__ ws)
{
    const int blk = blockIdx.x;
    const float* src; bf16_t* dst; int off;
    if      (blk <  2048) { src = qw; dst = ws;            off = blk;         }
    else if (blk <  3072) { src = kw; dst = ws +  4194304; off = blk -  2048; }
    else if (blk <  4096) { src = vw; dst = ws +  6291456; off = blk -  3072; }
    else if (blk <  6144) { src = ow; dst = ws +  8388608; off = blk -  4096; }
    else if (blk < 11776) { src = gw; dst = ws + 12582912; off = blk -  6144; }
    else if (blk < 17408) { src = uw; dst = ws + 24117248; off = blk - 11776; }
    else                  { src = dw; dst = ws + 35651584; off = blk - 17408; }

    int i = (off * 256 + threadIdx.x) * 8;
    f32x4 a = *(const f32x4*)(src + i);
    f32x4 b = *(const f32x4*)(src + i + 4);
    bf16x8 y;
#pragma unroll
    for (int e = 0; e < 4; ++e) { y[e] = (bf16_t)a[e]; y[e + 4] = (bf16_t)b[e]; }
    *(bf16x8*)(dst + i) = y;
}

// ---------------------------------------------------------------------------
// RMSNorm (fp32 in -> bf16 out)
// ---------------------------------------------------------------------------
__global__ __launch_bounds__(256)
void rmsnorm_f32(const float* __restrict__ X, const float* __restrict__ Wt,
                 bf16_t* __restrict__ Y)
{
    __shared__ float red[4];
    const int tid = threadIdx.x;
    const size_t row = blockIdx.x;
    const float* x = X + row * 2048;

    f32x4 x0 = *(const f32x4*)(x + tid * 8);
    f32x4 x1 = *(const f32x4*)(x + tid * 8 + 4);
    float ss = 0.f;
#pragma unroll
    for (int e = 0; e < 4; ++e) ss += x0[e] * x0[e] + x1[e] * x1[e];
#pragma unroll
    for (int off = 32; off; off >>= 1) ss += __shfl_xor(ss, off, 64);
    if ((tid & 63) == 0) red[tid >> 6] = ss;
    __syncthreads();
    float tot = red[0] + red[1] + red[2] + red[3];
    float scale = rsqrtf(tot * (1.f / 2048.f) + 1e-6f);

    f32x4 w0 = *(const f32x4*)(Wt + tid * 8);
    f32x4 w1 = *(const f32x4*)(Wt + tid * 8 + 4);
    bf16x8 yv;
#pragma unroll
    for (int e = 0; e < 4; ++e) {
        yv[e]     = (bf16_t)(x0[e] * scale * w0[e]);
        yv[e + 4] = (bf16_t)(x1[e] * scale * w1[e]);
    }
    *(bf16x8*)(Y + row * 2048 + tid * 8) = yv;
}

// ---------------------------------------------------------------------------
// RMSNorm (bf16 in -> bf16 out), fp32 gamma
// ---------------------------------------------------------------------------
__global__ __launch_bounds__(256)
void rmsnorm_bf16(const bf16_t* __restrict__ X, const float* __restrict__ Wt,
                  bf16_t* __restrict__ Y)
{
    __shared__ float red[4];
    const int tid = threadIdx.x;
    const size_t row = blockIdx.x;

    bf16x8 xv = *(const bf16x8*)(X + row * 2048 + tid * 8);
    float xf[8];
    float ss = 0.f;
#pragma unroll
    for (int e = 0; e < 8; ++e) { xf[e] = (float)xv[e]; ss += xf[e] * xf[e]; }
#pragma unroll
    for (int off = 32; off; off >>= 1) ss += __shfl_xor(ss, off, 64);
    if ((tid & 63) == 0) red[tid >> 6] = ss;
    __syncthreads();
    float tot = red[0] + red[1] + red[2] + red[3];
    float scale = rsqrtf(tot * (1.f / 2048.f) + 1e-6f);

    f32x4 w0 = *(const f32x4*)(Wt + tid * 8);
    f32x4 w1 = *(const f32x4*)(Wt + tid * 8 + 4);
    bf16x8 yv;
#pragma unroll
    for (int e = 0; e < 4; ++e) {
        yv[e]     = (bf16_t)(xf[e] * scale * w0[e]);
        yv[e + 4] = (bf16_t)(xf[e + 4] * scale * w1[e]);
    }
    *(bf16x8*)(Y + row * 2048 + tid * 8) = yv;
}

// ---------------------------------------------------------------------------
// Fused QKV projection: 256x256-tile GEMM (m201 geometry: 8 waves 2Mx4N,
// per-wave 128x64, 128 KiB dbuf LDS, 4 phases x 16 MFMA per K-tile, counted
// vmcnt(2), T2 swizzle, T5 setprio). W = wq||wk||wv as [4096, K].
// Grid MUST be 256 (M=4096 -> 16 M-panels x 16 N-panels).
// Epilogue splits cols: [0,2048) -> Qb (stride 2048), [2048,3072) -> Kb,
// [3072,4096) -> Vb (stride 1024).
// ---------------------------------------------------------------------------
__global__ __launch_bounds__(512, 1)
void gemm_qkv(const bf16_t* __restrict__ A, const bf16_t* __restrict__ W,
              bf16_t* __restrict__ Qb, bf16_t* __restrict__ Kb,
              bf16_t* __restrict__ Vb, int K)
{
    __shared__ bf16_t As[2][256 * 64];   // 64 KiB
    __shared__ bf16_t Ws[2][256 * 64];   // 64 KiB

    const int tid  = threadIdx.x;
    const int lane = tid & 63, wave = tid >> 6;
    const int quad = lane >> 4, l16 = lane & 15;
    const int wr = wave >> 2, wc = wave & 3;   // 2M x 4N waves, 128x64 each

    const int lid = (int)blockIdx.x;           // 256 blocks
    const int swz = (lid & 7) * 32 + (lid >> 3);
    const int bym = swz & 15, bxn = swz >> 4;
    const int m0 = bym * 256, n0 = bxn * 256;

    const bf16_t* Ab = A + (size_t)m0 * K;
    const bf16_t* Wb = W + (size_t)n0 * K;

    const int xsw  = (l16 & 7) << 3;
    const int aoff = (wr * 128 + l16) * 64;
    const int boff = (wc * 64 + l16) * 64;

    f32x4 acc[8][4] = {};

    // prologue: stage tile 0 fully (8 loads/thread)
    lds_stage2(Ab, As[0], 0,    tid, K, 0);
    lds_stage2(Ab, As[0], 1024, tid, K, 0);
    lds_stage2(Wb, Ws[0], 0,    tid, K, 0);
    lds_stage2(Wb, Ws[0], 1024, tid, K, 0);

    const int NT = K >> 6;
    for (int t = 0; t < NT; ++t) {
        const int b  = t & 1;
        const int kn = (t + 1) << 6;
        const bool pf = (t + 1 < NT);
        bf16_t* An = As[1 - b];
        bf16_t* Wn = Ws[1 - b];

        if (pf) {
            lds_stage2(Ab, An, 0, tid, K, kn);
            // drain tile t's 8 loads; keep the 2 just issued in flight
            asm volatile("s_waitcnt vmcnt(2)" ::: "memory");
        } else {
            asm volatile("s_waitcnt vmcnt(0)" ::: "memory");
        }
        __builtin_amdgcn_s_barrier();

        const bf16_t* Asb = As[b];
        const bf16_t* Wsb = Ws[b];
        bf16x8 af[4], bb[4];

        // ---- P0: ks=0, A rows lo + B (8 reads -> 16 MFMA) ----
        {
            const int kxo = (quad * 8) ^ xsw;
#pragma unroll
            for (int i = 0; i < 4; ++i)
                af[i] = *(const bf16x8*)(Asb + aoff + i * 1024 + kxo);
#pragma unroll
            for (int j = 0; j < 4; ++j)
                bb[j] = *(const bf16x8*)(Wsb + boff + j * 1024 + kxo);
        }
        if (pf) lds_stage2(Ab, An, 1024, tid, K, kn);
        __builtin_amdgcn_s_barrier();
        __builtin_amdgcn_s_setprio(1);
#pragma unroll
        for (int i = 0; i < 4; ++i)
#pragma unroll
            for (int j = 0; j < 4; ++j)
                acc[i][j] = MFMA16(af[i], bb[j], acc[i][j]);
        __builtin_amdgcn_s_setprio(0);
        __builtin_amdgcn_s_barrier();

        // ---- P1: ks=0, A rows hi (4 reads -> 16 MFMA) ----
        {
            const int kxo = (quad * 8) ^ xsw;
#pragma unroll
            for (int i = 0; i < 4; ++i)
                af[i] = *(const bf16x8*)(Asb + aoff + (i + 4) * 1024 + kxo);
        }
        if (pf) lds_stage2(Wb, Wn, 0, tid, K, kn);
        __builtin_amdgcn_s_barrier();
        __builtin_amdgcn_s_setprio(1);
#pragma unroll
        for (int i = 0; i < 4; ++i)
#pragma unroll
            for (int j = 0; j < 4; ++j)
                acc[i + 4][j] = MFMA16(af[i], bb[j], acc[i + 4][j]);
        __builtin_amdgcn_s_setprio(0);
        __builtin_amdgcn_s_barrier();

        // ---- P2: ks=1, A rows lo + B (8 reads -> 16 MFMA) ----
        {
            const int kxo = (32 + quad * 8) ^ xsw;
#pragma unroll
            for (int i = 0; i < 4; ++i)
                af[i] = *(const bf16x8*)(Asb + aoff + i * 1024 + kxo);
#pragma unroll
            for (int j = 0; j < 4; ++j)
                bb[j] = *(const bf16x8*)(Wsb + boff + j * 1024 + kxo);
        }
        if (pf) lds_stage2(Wb, Wn, 1024, tid, K, kn);
        __builtin_amdgcn_s_barrier();
        __builtin_amdgcn_s_setprio(1);
#pragma unroll
        for (int i = 0; i < 4; ++i)
#pragma unroll
            for (int j = 0; j < 4; ++j)
                acc[i][j] = MFMA16(af[i], bb[j], acc[i][j]);
        __builtin_amdgcn_s_setprio(0);
        __builtin_amdgcn_s_barrier();

        // ---- P3: ks=1, A rows hi (4 reads -> 16 MFMA) ----
        {
            const int kxo = (32 + quad * 8) ^ xsw;
#pragma unroll
            for (int i = 0; i < 4; ++i)
                af[i] = *(const bf16x8*)(Asb + aoff + (i + 4) * 1024 + kxo);
        }
        __builtin_amdgcn_s_barrier();
        __builtin_amdgcn_s_setprio(1);
#pragma unroll
        for (int i = 0; i < 4; ++i)
#pragma unroll
            for (int j = 0; j < 4; ++j)
                acc[i + 4][j] = MFMA16(af[i], bb[j], acc[i + 4][j]);
        __builtin_amdgcn_s_setprio(0);
        __builtin_amdgcn_s_barrier();
    }

    // epilogue: split store into Q / K / V buffers
#pragma unroll
    for (int i = 0; i < 8; ++i)
#pragma unroll
        for (int j = 0; j < 4; ++j)
#pragma unroll
            for (int r = 0; r < 4; ++r) {
                size_t row = (size_t)(m0 + wr * 128 + i * 16 + quad * 4 + r);
                int    col = n0 + wc * 64 + j * 16 + l16;
                bf16_t v = (bf16_t)acc[i][j][r];
                if (col < 2048)      Qb[row * 2048 + col] = v;
                else if (col < 3072) Kb[row * 1024 + (col - 2048)] = v;
                else                 Vb[row * 1024 + (col - 3072)] = v;
            }
}

// ---------------------------------------------------------------------------
// 8-phase GEMM, tile 256x128, 8 waves 4Mx2N (per-wave 64x64), 96 KiB dbuf
// LDS, 2 phases/K-tile, counted vmcnt(2). Grid = (M/256)*nbx, %8==0.
// mode 0: Cb=acc | 1: Cb=acc+Rf(f32) | 2: Cf=acc+Rb(bf16)
// ---------------------------------------------------------------------------
__global__ __launch_bounds__(512, 2)
void gemm8(const bf16_t* __restrict__ A, const bf16_t* __restrict__ W,
           const float* __restrict__ Rf, const bf16_t* __restrict__ Rb,
           bf16_t* __restrict__ Cb, float* __restrict__ Cf,
           int M, int N, int K, int nbx, int mode)
{
    __shared__ bf16_t As[2][256 * 64];   // 64 KiB
    __shared__ bf16_t Ws[2][128 * 64];   // 32 KiB

    const int tid  = threadIdx.x;
    const int lane = tid & 63, wave = tid >> 6;
    const int quad = lane >> 4, l16 = lane & 15;
    const int wr = wave >> 1, wc = wave & 1;   // 4M x 2N wave grid

    const int lid = (int)blockIdx.x;
    const int nwg = (M >> 8) * nbx;
    const int q   = nwg >> 3;
    const int swz = (lid & 7) * q + (lid >> 3);
    const int bxn = swz >> 4;
    const int bym = swz & 15;
    const int m0 = bym * 256, n0 = bxn * 128;

    const bf16_t* Ab = A + (size_t)m0 * K;
    const bf16_t* Wb = W + (size_t)n0 * K;

    const int xsw  = (l16 & 7) << 3;
    const int aoff = (wr * 64 + l16) * 64;
    const int boff = (wc * 64 + l16) * 64;

    f32x4 acc[4][4] = {};

    lds_stage2(Ab, As[0], 0,    tid, K, 0);
    lds_stage2(Ab, As[0], 1024, tid, K, 0);
    lds_stage2(Wb, Ws[0], 0,    tid, K, 0);

    const int NT = K >> 6;
    for (int t = 0; t < NT; ++t) {
        const int b  = t & 1;
        const int kn = (t + 1) << 6;
        const bool pf = (t + 1 < NT);
        bf16_t* An = As[1 - b];
        bf16_t* Wn = Ws[1 - b];

        if (pf) {
            lds_stage2(Ab, An, 0, tid, K, kn);
            asm volatile("s_waitcnt vmcnt(2)" ::: "memory");
        } else {
            asm volatile("s_waitcnt vmcnt(0)" ::: "memory");
        }
        __builtin_amdgcn_s_barrier();

        const bf16_t* Asb = As[b];
        const bf16_t* Wsb = Ws[b];

#pragma unroll
        for (int ks = 0; ks < 2; ++ks) {
            const int kxo = (ks * 32 + quad * 8) ^ xsw;
            bf16x8 af[4], bf_[4];
#pragma unroll
            for (int i = 0; i < 4; ++i)
                af[i] = *(const bf16x8*)(Asb + aoff + i * 1024 + kxo);
#pragma unroll
            for (int j = 0; j < 4; ++j)
                bf_[j] = *(const bf16x8*)(Wsb + boff + j * 1024 + kxo);
            if (pf) {
                if (ks == 0) lds_stage2(Ab, An, 1024, tid, K, kn);
                else         lds_stage2(Wb, Wn, 0,    tid, K, kn);
            }
            __builtin_amdgcn_s_barrier();
            __builtin_amdgcn_s_setprio(1);
#pragma unroll
            for (int i = 0; i < 4; ++i)
#pragma unroll
                for (int j = 0; j < 4; ++j)
                    acc[i][j] = MFMA16(af[i], bf_[j], acc[i][j]);
            __builtin_amdgcn_s_setprio(0);
            __builtin_amdgcn_s_barrier();
        }
    }

#pragma unroll
    for (int i = 0; i < 4; ++i)
#pragma unroll
        for (int j = 0; j < 4; ++j)
#pragma unroll
            for (int r = 0; r < 4; ++r) {
                size_t row = (size_t)(m0 + wr * 64 + i * 16 + quad * 4 + r);
                size_t col = (size_t)(n0 + wc * 64 + j * 16 + l16);
                float v = acc[i][j][r];
                if (mode == 1) v += Rf[row * (size_t)N + col];
                if (mode == 2)
                    Cf[row * (size_t)N + col] = v + (float)Rb[row * (size_t)N + col];
                else
                    Cb[row * (size_t)N + col] = (bf16_t)v;
            }
}

// ---------------------------------------------------------------------------
// Fused gate+up SwiGLU GEMM (round-2 version, measured ~203 us).
// ---------------------------------------------------------------------------
__global__ __launch_bounds__(512, 2)
void gateup8(const bf16_t* __restrict__ A, const bf16_t* __restrict__ G,
             const bf16_t* __restrict__ U, bf16_t* __restrict__ C,
             int M, int N, int K)
{
    __shared__ bf16_t As[2][256 * 64];   // 64 KiB
    __shared__ bf16_t Gs[2][128 * 64];   // 32 KiB
    __shared__ bf16_t Us[2][128 * 64];   // 32 KiB

    const int tid  = threadIdx.x;
    const int lane = tid & 63;
    const int wave = tid >> 6;
    const int quad = lane >> 4, l16 = lane & 15;
    const int wr = wave >> 2, wc = wave & 3;      // 2M x 4N wave grid

    const int lid = (int)blockIdx.x;
    const int nwg = (M >> 8) * (N >> 7);          // 16 * 44 = 704
    const int cpx = nwg >> 3;                     // 88
    const int swz = (lid & 7) * cpx + (lid >> 3);
    const int bxn = swz >> 4;                     // N-block (44)
    const int bym = swz & 15;                     // M-block (16)
    const int m0 = bym * 256, n0 = bxn * 128;

    const bf16_t* Ab = A + (size_t)m0 * K;
    const bf16_t* Gb = G + (size_t)n0 * K;
    const bf16_t* Ub = U + (size_t)n0 * K;

    const int xsw  = (l16 & 7) << 3;              // T2 read-side XOR (elems)
    const int aoff = (wr * 128 + l16) * 64;
    const int boff = (wc * 32 + l16) * 64;

    f32x4 accg[8][2] = {};
    f32x4 accu[8][2] = {};

    lds_stage2(Ab, As[0], 0,    tid, K, 0);
    lds_stage2(Ab, As[0], 1024, tid, K, 0);
    lds_stage2(Gb, Gs[0], 0,    tid, K, 0);
    lds_stage2(Ub, Us[0], 0,    tid, K, 0);

    const int NT = K >> 6;                        // 32 K-tiles
    for (int t = 0; t < NT; ++t) {
        const int b  = t & 1;
        const int kn = (t + 1) << 6;
        const bool pf = (t + 1 < NT);
        bf16_t* An = As[1 - b];
        bf16_t* Gn = Gs[1 - b];
        bf16_t* Un = Us[1 - b];

        if (pf) {
            lds_stage2(Ab, An, 0, tid, K, kn);
            asm volatile("s_waitcnt vmcnt(2)" ::: "memory");
        } else {
            asm volatile("s_waitcnt vmcnt(0)" ::: "memory");
        }
        __builtin_amdgcn_s_barrier();

        const bf16_t* Asb = As[b];
        const bf16_t* Gsb = Gs[b];
        const bf16_t* Usb = Us[b];

        bf16x8 af[4], bg[2], bu[2];

        // ---- P0: ks=0, A rows lo ----
        {
            const int kxo = (quad * 8) ^ xsw;
#pragma unroll
            for (int i = 0; i < 4; ++i)
                af[i] = *(const bf16x8*)(Asb + aoff + i * 1024 + kxo);
#pragma unroll
            for (int j = 0; j < 2; ++j) {
                bg[j] = *(const bf16x8*)(Gsb + boff + j * 1024 + kxo);
                bu[j] = *(const bf16x8*)(Usb + boff + j * 1024 + kxo);
            }
        }
        if (pf) lds_stage2(Ab, An, 1024, tid, K, kn);
        __builtin_amdgcn_s_barrier();
        __builtin_amdgcn_s_setprio(1);
#pragma unroll
        for (int i = 0; i < 4; ++i)
#pragma unroll
            for (int j = 0; j < 2; ++j) {
                accg[i][j] = MFMA16(af[i], bg[j], accg[i][j]);
                accu[i][j] = MFMA16(af[i], bu[j], accu[i][j]);
            }
        __builtin_amdgcn_s_setprio(0);
        __builtin_amdgcn_s_barrier();

        // ---- P1: ks=0, A rows hi ----
        {
            const int kxo = (quad * 8) ^ xsw;
#pragma unroll
            for (int i = 0; i < 4; ++i)
                af[i] = *(const bf16x8*)(Asb + aoff + (i + 4) * 1024 + kxo);
        }
        if (pf) lds_stage2(Gb, Gn, 0, tid, K, kn);
        __builtin_amdgcn_s_barrier();
        __builtin_amdgcn_s_setprio(1);
#pragma unroll
        for (int i = 0; i < 4; ++i)
#pragma unroll
            for (int j = 0; j < 2; ++j) {
                accg[i + 4][j] = MFMA16(af[i], bg[j], accg[i + 4][j]);
                accu[i + 4][j] = MFMA16(af[i], bu[j], accu[i + 4][j]);
            }
        __builtin_amdgcn_s_setprio(0);
        __builtin_amdgcn_s_barrier();

        // ---- P2: ks=1, A rows lo ----
        {
            const int kxo = (32 + quad * 8) ^ xsw;
#pragma unroll
            for (int i = 0; i < 4; ++i)
                af[i] = *(const bf16x8*)(Asb + aoff + i * 1024 + kxo);
#pragma unroll
            for (int j = 0; j < 2; ++j) {
                bg[j] = *(const bf16x8*)(Gsb + boff + j * 1024 + kxo);
                bu[j] = *(const bf16x8*)(Usb + boff + j * 1024 + kxo);
            }
        }
        if (pf) lds_stage2(Ub, Un, 0, tid, K, kn);
        __builtin_amdgcn_s_barrier();
        __builtin_amdgcn_s_setprio(1);
#pragma unroll
        for (int i = 0; i < 4; ++i)
#pragma unroll
            for (int j = 0; j < 2; ++j) {
                accg[i][j] = MFMA16(af[i], bg[j], accg[i][j]);
                accu[i][j] = MFMA16(af[i], bu[j], accu[i][j]);
            }
        __builtin_amdgcn_s_setprio(0);
        __builtin_amdgcn_s_barrier();

        // ---- P3: ks=1, A rows hi ----
        {
            const int kxo = (32 + quad * 8) ^ xsw;
#pragma unroll
            for (int i = 0; i < 4; ++i)
                af[i] = *(const bf16x8*)(Asb + aoff + (i + 4) * 1024 + kxo);
        }
        __builtin_amdgcn_s_barrier();
        __builtin_amdgcn_s_setprio(1);
#pragma unroll
        for (int i = 0; i < 4; ++i)
#pragma unroll
            for (int j = 0; j < 2; ++j) {
                accg[i + 4][j] = MFMA16(af[i], bg[j], accg[i + 4][j]);
                accu[i + 4][j] = MFMA16(af[i], bu[j], accu[i + 4][j]);
            }
        __builtin_amdgcn_s_setprio(0);
        __builtin_amdgcn_s_barrier();
    }

#pragma unroll
    for (int i = 0; i < 8; ++i)
#pragma unroll
        for (int j = 0; j < 2; ++j)
#pragma unroll
            for (int r = 0; r < 4; ++r) {
                size_t row = (size_t)(m0 + wr * 128 + i * 16 + quad * 4 + r);
                size_t col = (size_t)(n0 + wc * 32 + j * 16 + l16);
                float g = accg[i][j][r];
                float u = accu[i][j][r];
                float sig = 1.f / (1.f + __expf(fminf(-g, 80.f)));
                C[row * (size_t)N + col] = (bf16_t)(g * sig * u);
            }
}

// ---------------------------------------------------------------------------
// FALLBACK GEMM (fp32 weights staged in registers)
// ---------------------------------------------------------------------------
__global__ __launch_bounds__(256, 2)
void gemm_bt(const bf16_t* __restrict__ A, const float* __restrict__ W,
             const float* __restrict__ Rf, const bf16_t* __restrict__ Rb,
             bf16_t* __restrict__ Cb, float* __restrict__ Cf,
             int M, int N, int K, int mode)
{
    __shared__ bf16_t As[128 * 64];
    __shared__ bf16_t Ws[128 * 64];

    const int tid  = threadIdx.x;
    const int lane = tid & 63, wave = tid >> 6;
    const int quad = lane >> 4, l16 = lane & 15;
    const int m0 = blockIdx.y * 128, n0 = blockIdx.x * 128;
    const int wm = (wave >> 1) * 64, wn = (wave & 1) * 64;

    f32x4 acc[4][4] = {};

    for (int k0 = 0; k0 < K; k0 += 64) {
        bf16x8 ra[4];
        bf16x4 rw[8];
#pragma unroll
        for (int i = 0; i < 4; ++i) {
            int u = i * 256 + tid;
            int r = u >> 3, c = (u & 7) << 3;
            ra[i] = *(const bf16x8*)(A + (size_t)(m0 + r) * K + k0 + c);
        }
#pragma unroll
        for (int i = 0; i < 8; ++i) {
            int u = i * 256 + tid;
            int r = u >> 4, c = (u & 15) << 2;
            f32x4 w4 = *(const f32x4*)(W + (size_t)(n0 + r) * K + k0 + c);
#pragma unroll
            for (int e = 0; e < 4; ++e) rw[i][e] = (bf16_t)w4[e];
        }
        __syncthreads();
#pragma unroll
        for (int i = 0; i < 4; ++i)
            *(bf16x8*)(As + (i * 256 + tid) * 8) = ra[i];
#pragma unroll
        for (int i = 0; i < 8; ++i)
            *(bf16x4*)(Ws + (i * 256 + tid) * 4) = rw[i];
        __syncthreads();

#pragma unroll
        for (int ks = 0; ks < 64; ks += 32) {
            bf16x8 af[4], bfr[4];
#pragma unroll
            for (int i = 0; i < 4; ++i)
                af[i] = *(const bf16x8*)(As + (wm + i * 16 + l16) * 64 + ks + quad * 8);
#pragma unroll
            for (int j = 0; j < 4; ++j)
                bfr[j] = *(const bf16x8*)(Ws + (wn + j * 16 + l16) * 64 + ks + quad * 8);
#pragma unroll
            for (int i = 0; i < 4; ++i)
#pragma unroll
                for (int j = 0; j < 4; ++j)
                    acc[i][j] = MFMA16(af[i], bfr[j], acc[i][j]);
        }
    }

#pragma unroll
    for (int i = 0; i < 4; ++i)
#pragma unroll
        for (int j = 0; j < 4; ++j)
#pragma unroll
            for (int r = 0; r < 4; ++r) {
                size_t row = (size_t)(m0 + wm + i * 16 + quad * 4 + r);
                size_t col = (size_t)(n0 + wn + j * 16 + l16);
                float v = acc[i][j][r];
                if (mode == 1) v += Rf[row * (size_t)N + col];
                if (mode == 2)
                    Cf[row * (size_t)N + col] = v + (float)Rb[row * (size_t)N + col];
                else
                    Cb[row * (size_t)N + col] = (bf16_t)v;
            }
}

// ---------------------------------------------------------------------------
// FALLBACK fused gate+up (fp32 weights)
// ---------------------------------------------------------------------------
__global__ __launch_bounds__(256, 2)
void gemm_gateup(const bf16_t* __restrict__ A, const float* __restrict__ G,
                 const float* __restrict__ U, bf16_t* __restrict__ C,
                 int M, int N, int K)
{
    __shared__ bf16_t As[128 * 64];
    __shared__ bf16_t Gs[128 * 64];
    __shared__ bf16_t Us[128 * 64];

    const int tid  = threadIdx.x;
    const int lane = tid & 63, wave = tid >> 6;
    const int quad = lane >> 4, l16 = lane & 15;
    const int m0 = blockIdx.y * 128, n0 = blockIdx.x * 128;
    const int wm = (wave >> 1) * 64, wn = (wave & 1) * 64;

    f32x4 accg[4][4] = {};
    f32x4 accu[4][4] = {};

    for (int k0 = 0; k0 < K; k0 += 64) {
        bf16x8 ra[4];
        bf16x4 rg[8], ru[8];
#pragma unroll
        for (int i = 0; i < 4; ++i) {
            int u = i * 256 + tid;
            int r = u >> 3, c = (u & 7) << 3;
            ra[i] = *(const bf16x8*)(A + (size_t)(m0 + r) * K + k0 + c);
        }
#pragma unroll
        for (int i = 0; i < 8; ++i) {
            int u = i * 256 + tid;
            int r = u >> 4, c = (u & 15) << 2;
            f32x4 g4 = *(const f32x4*)(G + (size_t)(n0 + r) * K + k0 + c);
            f32x4 u4 = *(const f32x4*)(U + (size_t)(n0 + r) * K + k0 + c);
#pragma unroll
            for (int e = 0; e < 4; ++e) { rg[i][e] = (bf16_t)g4[e]; ru[i][e] = (bf16_t)u4[e]; }
        }
        __syncthreads();
#pragma unroll
        for (int i = 0; i < 4; ++i)
            *(bf16x8*)(As + (i * 256 + tid) * 8) = ra[i];
#pragma unroll
        for (int i = 0; i < 8; ++i) {
            *(bf16x4*)(Gs + (i * 256 + tid) * 4) = rg[i];
            *(bf16x4*)(Us + (i * 256 + tid) * 4) = ru[i];
        }
        __syncthreads();

#pragma unroll
        for (int ks = 0; ks < 64; ks += 32) {
            bf16x8 af[4], bg[4], bu[4];
#pragma unroll
            for (int i = 0; i < 4; ++i)
                af[i] = *(const bf16x8*)(As + (wm + i * 16 + l16) * 64 + ks + quad * 8);
#pragma unroll
            for (int j = 0; j < 4; ++j) {
                bg[j] = *(const bf16x8*)(Gs + (wn + j * 16 + l16) * 64 + ks + quad * 8);
                bu[j] = *(const bf16x8*)(Us + (wn + j * 16 + l16) * 64 + ks + quad * 8);
            }
#pragma unroll
            for (int i = 0; i < 4; ++i)
#pragma unroll
                for (int j = 0; j < 4; ++j) {
                    accg[i][j] = MFMA16(af[i], bg[j], accg[i][j]);
                    accu[i][j] = MFMA16(af[i], bu[j], accu[i][j]);
                }
        }
    }

#pragma unroll
    for (int i = 0; i < 4; ++i)
#pragma unroll
        for (int j = 0; j < 4; ++j)
#pragma unroll
            for (int r = 0; r < 4; ++r) {
                size_t row = (size_t)(m0 + wm + i * 16 + quad * 4 + r);
                size_t col = (size_t)(n0 + wn + j * 16 + l16);
                float g = accg[i][j][r];
                float u = accu[i][j][r];
                float sig = 1.f / (1.f + __expf(fminf(-g, 80.f)));
                C[row * (size_t)N + col] = (bf16_t)(g * sig * u);
            }
}

// ---------------------------------------------------------------------------
// Flash attention fwd (round-4 structure + diagonal-only mask + setprio).
// kvs = row stride of K/V buffers (1024 = separate contiguous buffers).
// ---------------------------------------------------------------------------
__global__ __launch_bounds__(256, 2)
void attn_fwd(const bf16_t* __restrict__ Q, const bf16_t* __restrict__ Kg,
              const bf16_t* __restrict__ Vg, bf16_t* __restrict__ O, int kvs)
{
    __shared__ bf16_t Ks[2][64 * 128];   // col XOR-swizzled by (row&7)<<3
    __shared__ bf16_t Vt[2][128 * 64];   // Vt[d][kb], slot = kb^(d&7)
    __shared__ bf16_t Pl[4][16 * 72];    // padded stride 72

    const int tid  = threadIdx.x;
    const int lane = tid & 63, wave = tid >> 6;
    const int quad = lane >> 4, l16 = lane & 15;
    const int bh = blockIdx.y, b = bh >> 4, h = bh & 15;

    const bf16_t* Qh = Q  + (size_t)b * 2048 * 2048 + (size_t)h * 128;
    const bf16_t* Kh = Kg + (size_t)b * 2048 * kvs + (size_t)(h >> 1) * 128;
    const bf16_t* Vh = Vg + (size_t)b * 2048 * kvs + (size_t)(h >> 1) * 128;

    const float scale = 0.08838834764831845f;   // 1/sqrt(128)

    const int krow = tid >> 4;            // K row within 16-row group
    const int kcol = (tid & 15) << 3;     // K col (8-elem granule)
    const int vd   = tid & 127;           // V transpose: d
    const int vkb  = tid >> 7;            // V transpose: kb base (+2*it)

#pragma unroll 1
    for (int pass = 0; pass < 2; ++pass) {
        const int qt = pass ? (31 - (int)blockIdx.x) : (int)blockIdx.x;
        const int q0 = qt * 64;

        bf16x8 aq[4];
#pragma unroll
        for (int ks = 0; ks < 4; ++ks)
            aq[ks] = *(const bf16x8*)(Qh + (size_t)(q0 + wave * 16 + l16) * 2048 + ks * 32 + quad * 8);

        float m_r[4] = { -30000.f, -30000.f, -30000.f, -30000.f };
        float l_r[4] = { 0.f, 0.f, 0.f, 0.f };
        f32x4 acc_o[8] = {};

        const int ntiles = qt + 1;

        bf16x8 rk[4], rv[4];
        // ---- prologue: stage tile 0 into buf 0 ----
#pragma unroll
        for (int i = 0; i < 4; ++i)
            rk[i] = *(const bf16x8*)(Kh + (size_t)(i * 16 + krow) * kvs + kcol);
#pragma unroll
        for (int it = 0; it < 4; ++it)
#pragma unroll
            for (int j = 0; j < 8; ++j)
                rv[it][j] = Vh[(size_t)((vkb + 2 * it) * 8 + j) * kvs + vd];
#pragma unroll
        for (int i = 0; i < 4; ++i) {
            int row = i * 16 + krow;
            *(bf16x8*)(&Ks[0][row * 128 + (kcol ^ ((row & 7) << 3))]) = rk[i];
        }
#pragma unroll
        for (int it = 0; it < 4; ++it) {
            int kb = vkb + 2 * it;
            *(bf16x8*)(&Vt[0][vd * 64 + ((kb ^ (vd & 7)) << 3)]) = rv[it];
        }
        __syncthreads();

        for (int t = 0; t < ntiles; ++t) {
            const int bb = t & 1;
            const bool pf = (t + 1 < ntiles);
            const bool diag = (t == qt);
            const int kv0 = t * 64;
            const int kvn = kv0 + 64;

            if (pf) {   // early-issue next tile's global loads (regs)
#pragma unroll
                for (int i = 0; i < 4; ++i)
                    rk[i] = *(const bf16x8*)(Kh + (size_t)(kvn + i * 16 + krow) * kvs + kcol);
#pragma unroll
                for (int it = 0; it < 4; ++it)
#pragma unroll
                    for (int j = 0; j < 8; ++j)
                        rv[it][j] = Vh[(size_t)(kvn + (vkb + 2 * it) * 8 + j) * kvs + vd];
            }

            // ---- QK^T (swizzled Ks reads, conflict-free) ----
            f32x4 accs[4] = {};
            __builtin_amdgcn_s_setprio(1);
#pragma unroll
            for (int ks = 0; ks < 4; ++ks)
#pragma unroll
                for (int j = 0; j < 4; ++j) {
                    const int row = j * 16 + l16;
                    bf16x8 bk = *(const bf16x8*)(&Ks[bb][row * 128 + ((ks * 32 + quad * 8) ^ ((row & 7) << 3))]);
                    accs[j] = MFMA16(aq[ks], bk, accs[j]);
                }
            __builtin_amdgcn_s_setprio(0);

            // ---- online softmax (mask only on the diagonal tile) ----
#pragma unroll
            for (int r = 0; r < 4; ++r) {
                const int qrow = q0 + wave * 16 + quad * 4 + r;
                float s[4];
#pragma unroll
                for (int j = 0; j < 4; ++j) s[j] = accs[j][r] * scale;
                if (diag) {
#pragma unroll
                    for (int j = 0; j < 4; ++j)
                        if (kv0 + j * 16 + l16 > qrow) s[j] = -30000.f;
                }
                float mx = fmaxf(fmaxf(s[0], s[1]), fmaxf(s[2], s[3]));
                mx = fmaxf(mx, __shfl_xor(mx, 1, 64));
                mx = fmaxf(mx, __shfl_xor(mx, 2, 64));
                mx = fmaxf(mx, __shfl_xor(mx, 4, 64));
                mx = fmaxf(mx, __shfl_xor(mx, 8, 64));
                float mnew  = fmaxf(m_r[r], mx);
                float alpha = __expf(fmaxf(m_r[r] - mnew, -80.f));
                float rs = 0.f;
#pragma unroll
                for (int j = 0; j < 4; ++j) {
                    float p = __expf(fmaxf(s[j] - mnew, -80.f));
                    rs += p;
                    Pl[wave][(quad * 4 + r) * 72 + j * 16 + l16] = (bf16_t)p;
                }
                rs += __shfl_xor(rs, 1, 64);
                rs += __shfl_xor(rs, 2, 64);
                rs += __shfl_xor(rs, 4, 64);
                rs += __shfl_xor(rs, 8, 64);
                l_r[r] = l_r[r] * alpha + rs;
                m_r[r] = mnew;
#pragma unroll
                for (int nt = 0; nt < 8; ++nt) acc_o[nt][r] *= alpha;
            }

            // ---- PV (Pl is per-wave; compiler orders via lgkmcnt) ----
            __builtin_amdgcn_s_setprio(1);
#pragma unroll
            for (int ks2 = 0; ks2 < 2; ++ks2) {
                bf16x8 ap = *(const bf16x8*)(&Pl[wave][l16 * 72 + ks2 * 32 + quad * 8]);
                const int kb_r = ks2 * 4 + quad;
#pragma unroll
                for (int nt = 0; nt < 8; ++nt) {
                    const int d = nt * 16 + l16;
                    bf16x8 bv = *(const bf16x8*)(&Vt[bb][d * 64 + ((kb_r ^ (d & 7)) << 3)]);
                    acc_o[nt] = MFMA16(ap, bv, acc_o[nt]);
                }
            }
            __builtin_amdgcn_s_setprio(0);

            // ---- write prefetched tile into the other buffer ----
            if (pf) {
#pragma unroll
                for (int i = 0; i < 4; ++i) {
                    int row = i * 16 + krow;
                    *(bf16x8*)(&Ks[1 - bb][row * 128 + (kcol ^ ((row & 7) << 3))]) = rk[i];
                }
#pragma unroll
                for (int it = 0; it < 4; ++it) {
                    int kb = vkb + 2 * it;
                    *(bf16x8*)(&Vt[1 - bb][vd * 64 + ((kb ^ (vd & 7)) << 3)]) = rv[it];
                }
            }
            __syncthreads();   // buf[1-bb] writes visible; joint advance
        }

#pragma unroll
        for (int r = 0; r < 4; ++r) {
            float inv = 1.f / fmaxf(l_r[r], 1e-30f);
            size_t orow = (size_t)b * 2048 + q0 + wave * 16 + quad * 4 + r;
#pragma unroll
            for (int nt = 0; nt < 8; ++nt)
                O[orow * 2048 + h * 128 + nt * 16 + l16] = (bf16_t)(acc_o[nt][r] * inv);
        }
    }
}

// ---------------------------------------------------------------------------
// Launch. Fast path (ws >= 174 MB): single wconv dispatch, fused QKV gemm
// (256^2 template), attn, gemm8 O/down, gateup8. 8 dispatches total.
// Fallback: fp32-weight path. Branch on ws_size -> graph-capture safe.
// ---------------------------------------------------------------------------
extern "C" void kernel_launch(void* const* d_in, const int* in_sizes, int n_in,
                              void* d_out, int out_size, void* d_ws, size_t ws_size,
                              hipStream_t stream)
{
    const float* x   = (const float*)d_in[0];
    const float* qw  = (const float*)d_in[2];
    const float* kw  = (const float*)d_in[3];
    const float* vw  = (const float*)d_in[4];
    const float* ow  = (const float*)d_in[5];
    const float* gw  = (const float*)d_in[6];
    const float* uw  = (const float*)d_in[7];
    const float* dw  = (const float*)d_in[8];
    const float* ln1 = (const float*)d_in[9];
    const float* ln2 = (const float*)d_in[10];
    float*  out = (float*)d_out;
    bf16_t* ws  = (bf16_t*)d_ws;

    dim3 blk(256);
    const size_t NEED = 87031808ull * 2;   // 174 MB

    if (ws_size >= NEED) {
        // ---- fast path: bf16 weights + async-staged GEMMs ----
        bf16_t* wq = ws;                      // 4,194,304  (wq||wk||wv is the
        bf16_t* wo = ws + 8388608;            //  [4096,2048] QKV weight)
        bf16_t* wg = ws + 12582912;           // 11,534,336
        bf16_t* wu = ws + 24117248;           // 11,534,336
        bf16_t* wd = ws + 35651584;           // 11,534,336
        bf16_t* h1 = ws + 47185920;           // 8,388,608
        bf16_t* qb = ws + 55574528;           // 8,388,608 (later hb)
        bf16_t* kb = ws + 63963136;           // 4,194,304 (later gb)
        bf16_t* vb = ws + 68157440;           // 4,194,304
        bf16_t* ab = (bf16_t*)d_out;          // attn out scratch in d_out
        bf16_t* hb = qb;
        bf16_t* gb = kb;                      // 23,068,672 ends at 87,031,808

        wconv_all<<<23040, blk, 0, stream>>>(qw, kw, vw, ow, gw, uw, dw, ws);
        rmsnorm_f32<<<4096, blk, 0, stream>>>(x, ln1, h1);
        gemm_qkv<<<256, dim3(512), 0, stream>>>(h1, wq, qb, kb, vb, 2048);
        attn_fwd<<<dim3(16, 32), blk, 0, stream>>>(qb, kb, vb, ab, 1024);
        gemm8<<<256, dim3(512), 0, stream>>>(ab, wo, x, nullptr, hb, nullptr, 4096, 2048, 2048, 16, 1);
        rmsnorm_bf16<<<4096, blk, 0, stream>>>(hb, ln2, h1);
        gateup8<<<704, dim3(512), 0, stream>>>(h1, wg, wu, gb, 4096, 5632, 2048);
        gemm8<<<256, dim3(512), 0, stream>>>(gb, wd, nullptr, hb, nullptr, out, 4096, 2048, 5632, 16, 2);
    } else {
        // ---- fallback: fp32-weight path (78 MB) ----
        const size_t ME = 1ull << 20;
        bf16_t* h1 = ws;
        bf16_t* qb = ws + 8  * ME;
        bf16_t* kb = ws + 16 * ME;
        bf16_t* vb = ws + 20 * ME;
        bf16_t* ab = (bf16_t*)d_out;
        bf16_t* hb = ws + 8  * ME;
        bf16_t* gb = ws + 16 * ME;

        rmsnorm_f32<<<4096, blk, 0, stream>>>(x, ln1, h1);
        gemm_bt<<<dim3(16, 32), blk, 0, stream>>>(h1, qw, nullptr, nullptr, qb, nullptr, 4096, 2048, 2048, 0);
        gemm_bt<<<dim3( 8, 32), blk, 0, stream>>>(h1, kw, nullptr, nullptr, kb, nullptr, 4096, 1024, 2048, 0);
        gemm_bt<<<dim3( 8, 32), blk, 0, stream>>>(h1, vw, nullptr, nullptr, vb, nullptr, 4096, 1024, 2048, 0);
        attn_fwd<<<dim3(16, 32), blk, 0, stream>>>(qb, kb, vb, ab, 1024);
        gemm_bt<<<dim3(16, 32), blk, 0, stream>>>(ab, ow, x, nullptr, hb, nullptr, 4096, 2048, 2048, 1);
        rmsnorm_bf16<<<4096, blk, 0, stream>>>(hb, ln2, h1);
        gemm_gateup<<<dim3(44, 32), blk, 0, stream>>>(h1, gw, uw, gb, 4096, 5632, 2048);
        gemm_bt<<<dim3(16, 32), blk, 0, stream>>>(gb, dw, nullptr, hb, nullptr, out, 4096, 2048, 5632, 2);
    }
}

// Round 6
// 777.883 us; speedup vs baseline: 1.3631x; 1.0122x over previous
//
#include <hip/hip_runtime.h>
#include <stdint.h>

typedef __bf16 bf16_t;
typedef __bf16 bf16x8 __attribute__((ext_vector_type(8)));
typedef __bf16 bf16x4 __attribute__((ext_vector_type(4)));
typedef float  f32x4  __attribute__((ext_vector_type(4)));

#define MFMA16(a, b, c) __builtin_amdgcn_mfma_f32_16x16x32_bf16((a), (b), (c), 0, 0, 0)

// Async global->LDS 16B/lane. LDS dest is wave-uniform base + lane*16; our
// lds ptr is computed as base + lane*16, matching the HW contract (m97/m104).
__device__ __forceinline__ void load_lds16(const bf16_t* g, bf16_t* l)
{
    __builtin_amdgcn_global_load_lds(
        (const __attribute__((address_space(1))) uint32_t*)(uintptr_t)g,
        (__attribute__((address_space(3))) uint32_t*)(uint32_t)(uintptr_t)l,
        16, 0, 0);
}

// Stage 2x16B per thread into LDS with T2 inverse-swizzled global source.
// LDS linear slot u*16B holds global[row][ (x ^ ((row&7)<<3)) ] for x in the
// 8-elem group; readers apply the same XOR (involution, rule 21).
__device__ __forceinline__ void lds_stage2(const bf16_t* __restrict__ Gsrc,
                                           bf16_t* Ldst, int u0,
                                           int tid, int K, int k0)
{
#pragma unroll
    for (int l = 0; l < 2; ++l) {
        int u = u0 + l * 512 + tid;
        int row = u >> 3;
        int col = (((u & 7) ^ (row & 7)) << 3);
        load_lds16(Gsrc + (size_t)row * K + k0 + col, Ldst + u * 8);
    }
}

// ---------------------------------------------------------------------------
// All 7 weight conversions fp32 -> bf16 in ONE dispatch (segment by blockIdx).
// Each block converts exactly one 2048-elem row (256 thr x 8).
// gate/up rows are INTERLEAVED into wgu at 16-row granularity:
//   wgu[32t + r]      = wg[16t + r]   (r in [0,16))
//   wgu[32t + 16 + r] = wu[16t + r]
// so a 256-col GEMM tile holds gate at even 16-col granules, up at odd ones.
// ---------------------------------------------------------------------------
__global__ __launch_bounds__(256)
void wconv_all(const float* __restrict__ qw, const float* __restrict__ kw,
               const float* __restrict__ vw, const float* __restrict__ ow,
               const float* __restrict__ gw, const float* __restrict__ uw,
               const float* __restrict__ dw, bf16_t* __restrict__ ws)
{
    const int blk = blockIdx.x;
    const float* src; bf16_t* dst; size_t srow, drow;
    if      (blk <  2048) { src = qw; dst = ws;            srow = blk;         drow = srow; }
    else if (blk <  3072) { src = kw; dst = ws +  4194304; srow = blk -  2048; drow = srow; }
    else if (blk <  4096) { src = vw; dst = ws +  6291456; srow = blk -  3072; drow = srow; }
    else if (blk <  6144) { src = ow; dst = ws +  8388608; srow = blk -  4096; drow = srow; }
    else if (blk < 11776) { src = gw; dst = ws + 12582912; srow = blk -  6144;
                            drow = 32 * (srow >> 4) + (srow & 15); }
    else if (blk < 17408) { src = uw; dst = ws + 12582912; srow = blk - 11776;
                            drow = 32 * (srow >> 4) + 16 + (srow & 15); }
    else                  { src = dw; dst = ws + 35651584; srow = blk - 17408; drow = srow; }

    int c = threadIdx.x * 8;
    f32x4 a = *(const f32x4*)(src + srow * 2048 + c);
    f32x4 b = *(const f32x4*)(src + srow * 2048 + c + 4);
    bf16x8 y;
#pragma unroll
    for (int e = 0; e < 4; ++e) { y[e] = (bf16_t)a[e]; y[e + 4] = (bf16_t)b[e]; }
    *(bf16x8*)(dst + drow * 2048 + c) = y;
}

// ---------------------------------------------------------------------------
// RMSNorm (fp32 in -> bf16 out)
// ---------------------------------------------------------------------------
__global__ __launch_bounds__(256)
void rmsnorm_f32(const float* __restrict__ X, const float* __restrict__ Wt,
                 bf16_t* __restrict__ Y)
{
    __shared__ float red[4];
    const int tid = threadIdx.x;
    const size_t row = blockIdx.x;
    const float* x = X + row * 2048;

    f32x4 x0 = *(const f32x4*)(x + tid * 8);
    f32x4 x1 = *(const f32x4*)(x + tid * 8 + 4);
    float ss = 0.f;
#pragma unroll
    for (int e = 0; e < 4; ++e) ss += x0[e] * x0[e] + x1[e] * x1[e];
#pragma unroll
    for (int off = 32; off; off >>= 1) ss += __shfl_xor(ss, off, 64);
    if ((tid & 63) == 0) red[tid >> 6] = ss;
    __syncthreads();
    float tot = red[0] + red[1] + red[2] + red[3];
    float scale = rsqrtf(tot * (1.f / 2048.f) + 1e-6f);

    f32x4 w0 = *(const f32x4*)(Wt + tid * 8);
    f32x4 w1 = *(const f32x4*)(Wt + tid * 8 + 4);
    bf16x8 yv;
#pragma unroll
    for (int e = 0; e < 4; ++e) {
        yv[e]     = (bf16_t)(x0[e] * scale * w0[e]);
        yv[e + 4] = (bf16_t)(x1[e] * scale * w1[e]);
    }
    *(bf16x8*)(Y + row * 2048 + tid * 8) = yv;
}

// ---------------------------------------------------------------------------
// RMSNorm (bf16 in -> bf16 out), fp32 gamma
// ---------------------------------------------------------------------------
__global__ __launch_bounds__(256)
void rmsnorm_bf16(const bf16_t* __restrict__ X, const float* __restrict__ Wt,
                  bf16_t* __restrict__ Y)
{
    __shared__ float red[4];
    const int tid = threadIdx.x;
    const size_t row = blockIdx.x;

    bf16x8 xv = *(const bf16x8*)(X + row * 2048 + tid * 8);
    float xf[8];
    float ss = 0.f;
#pragma unroll
    for (int e = 0; e < 8; ++e) { xf[e] = (float)xv[e]; ss += xf[e] * xf[e]; }
#pragma unroll
    for (int off = 32; off; off >>= 1) ss += __shfl_xor(ss, off, 64);
    if ((tid & 63) == 0) red[tid >> 6] = ss;
    __syncthreads();
    float tot = red[0] + red[1] + red[2] + red[3];
    float scale = rsqrtf(tot * (1.f / 2048.f) + 1e-6f);

    f32x4 w0 = *(const f32x4*)(Wt + tid * 8);
    f32x4 w1 = *(const f32x4*)(Wt + tid * 8 + 4);
    bf16x8 yv;
#pragma unroll
    for (int e = 0; e < 4; ++e) {
        yv[e]     = (bf16_t)(xf[e] * scale * w0[e]);
        yv[e + 4] = (bf16_t)(xf[e + 4] * scale * w1[e]);
    }
    *(bf16x8*)(Y + row * 2048 + tid * 8) = yv;
}

// ---------------------------------------------------------------------------
// Fused QKV projection: 256x256-tile GEMM (8 waves 2Mx4N, per-wave 128x64,
// 128 KiB dbuf LDS, 4 phases x 16 MFMA per K-tile, counted vmcnt(2), T2
// swizzle, T5 setprio). W = wq||wk||wv as [4096, K]. Grid MUST be 256.
// Epilogue splits cols: [0,2048) -> Qb, [2048,3072) -> Kb, [3072,4096) -> Vb.
// ---------------------------------------------------------------------------
__global__ __launch_bounds__(512, 1)
void gemm_qkv(const bf16_t* __restrict__ A, const bf16_t* __restrict__ W,
              bf16_t* __restrict__ Qb, bf16_t* __restrict__ Kb,
              bf16_t* __restrict__ Vb, int K)
{
    __shared__ bf16_t As[2][256 * 64];   // 64 KiB
    __shared__ bf16_t Ws[2][256 * 64];   // 64 KiB

    const int tid  = threadIdx.x;
    const int lane = tid & 63, wave = tid >> 6;
    const int quad = lane >> 4, l16 = lane & 15;
    const int wr = wave >> 2, wc = wave & 3;   // 2M x 4N waves, 128x64 each

    const int lid = (int)blockIdx.x;           // 256 blocks
    const int swz = (lid & 7) * 32 + (lid >> 3);
    const int bym = swz & 15, bxn = swz >> 4;
    const int m0 = bym * 256, n0 = bxn * 256;

    const bf16_t* Ab = A + (size_t)m0 * K;
    const bf16_t* Wb = W + (size_t)n0 * K;

    const int xsw  = (l16 & 7) << 3;
    const int aoff = (wr * 128 + l16) * 64;
    const int boff = (wc * 64 + l16) * 64;

    f32x4 acc[8][4] = {};

    lds_stage2(Ab, As[0], 0,    tid, K, 0);
    lds_stage2(Ab, As[0], 1024, tid, K, 0);
    lds_stage2(Wb, Ws[0], 0,    tid, K, 0);
    lds_stage2(Wb, Ws[0], 1024, tid, K, 0);

    const int NT = K >> 6;
    for (int t = 0; t < NT; ++t) {
        const int b  = t & 1;
        const int kn = (t + 1) << 6;
        const bool pf = (t + 1 < NT);
        bf16_t* An = As[1 - b];
        bf16_t* Wn = Ws[1 - b];

        if (pf) {
            lds_stage2(Ab, An, 0, tid, K, kn);
            asm volatile("s_waitcnt vmcnt(2)" ::: "memory");
        } else {
            asm volatile("s_waitcnt vmcnt(0)" ::: "memory");
        }
        __builtin_amdgcn_s_barrier();

        const bf16_t* Asb = As[b];
        const bf16_t* Wsb = Ws[b];
        bf16x8 af[4], bb[4];

        // ---- P0: ks=0, A rows lo + B ----
        {
            const int kxo = (quad * 8) ^ xsw;
#pragma unroll
            for (int i = 0; i < 4; ++i)
                af[i] = *(const bf16x8*)(Asb + aoff + i * 1024 + kxo);
#pragma unroll
            for (int j = 0; j < 4; ++j)
                bb[j] = *(const bf16x8*)(Wsb + boff + j * 1024 + kxo);
        }
        if (pf) lds_stage2(Ab, An, 1024, tid, K, kn);
        __builtin_amdgcn_s_barrier();
        __builtin_amdgcn_s_setprio(1);
#pragma unroll
        for (int i = 0; i < 4; ++i)
#pragma unroll
            for (int j = 0; j < 4; ++j)
                acc[i][j] = MFMA16(af[i], bb[j], acc[i][j]);
        __builtin_amdgcn_s_setprio(0);
        __builtin_amdgcn_s_barrier();

        // ---- P1: ks=0, A rows hi ----
        {
            const int kxo = (quad * 8) ^ xsw;
#pragma unroll
            for (int i = 0; i < 4; ++i)
                af[i] = *(const bf16x8*)(Asb + aoff + (i + 4) * 1024 + kxo);
        }
        if (pf) lds_stage2(Wb, Wn, 0, tid, K, kn);
        __builtin_amdgcn_s_barrier();
        __builtin_amdgcn_s_setprio(1);
#pragma unroll
        for (int i = 0; i < 4; ++i)
#pragma unroll
            for (int j = 0; j < 4; ++j)
                acc[i + 4][j] = MFMA16(af[i], bb[j], acc[i + 4][j]);
        __builtin_amdgcn_s_setprio(0);
        __builtin_amdgcn_s_barrier();

        // ---- P2: ks=1, A rows lo + B ----
        {
            const int kxo = (32 + quad * 8) ^ xsw;
#pragma unroll
            for (int i = 0; i < 4; ++i)
                af[i] = *(const bf16x8*)(Asb + aoff + i * 1024 + kxo);
#pragma unroll
            for (int j = 0; j < 4; ++j)
                bb[j] = *(const bf16x8*)(Wsb + boff + j * 1024 + kxo);
        }
        if (pf) lds_stage2(Wb, Wn, 1024, tid, K, kn);
        __builtin_amdgcn_s_barrier();
        __builtin_amdgcn_s_setprio(1);
#pragma unroll
        for (int i = 0; i < 4; ++i)
#pragma unroll
            for (int j = 0; j < 4; ++j)
                acc[i][j] = MFMA16(af[i], bb[j], acc[i][j]);
        __builtin_amdgcn_s_setprio(0);
        __builtin_amdgcn_s_barrier();

        // ---- P3: ks=1, A rows hi ----
        {
            const int kxo = (32 + quad * 8) ^ xsw;
#pragma unroll
            for (int i = 0; i < 4; ++i)
                af[i] = *(const bf16x8*)(Asb + aoff + (i + 4) * 1024 + kxo);
        }
        __builtin_amdgcn_s_barrier();
        __builtin_amdgcn_s_setprio(1);
#pragma unroll
        for (int i = 0; i < 4; ++i)
#pragma unroll
            for (int j = 0; j < 4; ++j)
                acc[i + 4][j] = MFMA16(af[i], bb[j], acc[i + 4][j]);
        __builtin_amdgcn_s_setprio(0);
        __builtin_amdgcn_s_barrier();
    }

    // epilogue: split store into Q / K / V buffers
#pragma unroll
    for (int i = 0; i < 8; ++i)
#pragma unroll
        for (int j = 0; j < 4; ++j)
#pragma unroll
            for (int r = 0; r < 4; ++r) {
                size_t row = (size_t)(m0 + wr * 128 + i * 16 + quad * 4 + r);
                int    col = n0 + wc * 64 + j * 16 + l16;
                bf16_t v = (bf16_t)acc[i][j][r];
                if (col < 2048)      Qb[row * 2048 + col] = v;
                else if (col < 3072) Kb[row * 1024 + (col - 2048)] = v;
                else                 Vb[row * 1024 + (col - 3072)] = v;
            }
}

// ---------------------------------------------------------------------------
// Fused gate+up SwiGLU via INTERLEAVED weight (wgu [11264, K], 16-row
// granule alternating gate/up). Same 256x256-tile structure as gemm_qkv.
// In each wave's fragment, j-even accumulators are gate, j-odd are up for
// the SAME logical columns at the SAME lane -> lane-local SwiGLU epilogue.
// C[M, 5632]. Grid = 16 * 44 = 704 blocks (%8==0).
// ---------------------------------------------------------------------------
__global__ __launch_bounds__(512, 1)
void gateup_il(const bf16_t* __restrict__ A, const bf16_t* __restrict__ W,
               bf16_t* __restrict__ C, int K)
{
    __shared__ bf16_t As[2][256 * 64];   // 64 KiB
    __shared__ bf16_t Ws[2][256 * 64];   // 64 KiB

    const int tid  = threadIdx.x;
    const int lane = tid & 63, wave = tid >> 6;
    const int quad = lane >> 4, l16 = lane & 15;
    const int wr = wave >> 2, wc = wave & 3;   // 2M x 4N waves, 128x64 each

    const int lid = (int)blockIdx.x;           // 704 blocks
    const int swz = (lid & 7) * 88 + (lid >> 3);
    const int bxn = swz >> 4;                  // 0..43
    const int bym = swz & 15;                  // 0..15
    const int m0 = bym * 256, n0 = bxn * 256;  // n0 in interleaved space

    const bf16_t* Ab = A + (size_t)m0 * K;
    const bf16_t* Wb = W + (size_t)n0 * K;

    const int xsw  = (l16 & 7) << 3;
    const int aoff = (wr * 128 + l16) * 64;
    const int boff = (wc * 64 + l16) * 64;

    f32x4 acc[8][4] = {};

    lds_stage2(Ab, As[0], 0,    tid, K, 0);
    lds_stage2(Ab, As[0], 1024, tid, K, 0);
    lds_stage2(Wb, Ws[0], 0,    tid, K, 0);
    lds_stage2(Wb, Ws[0], 1024, tid, K, 0);

    const int NT = K >> 6;
    for (int t = 0; t < NT; ++t) {
        const int b  = t & 1;
        const int kn = (t + 1) << 6;
        const bool pf = (t + 1 < NT);
        bf16_t* An = As[1 - b];
        bf16_t* Wn = Ws[1 - b];

        if (pf) {
            lds_stage2(Ab, An, 0, tid, K, kn);
            asm volatile("s_waitcnt vmcnt(2)" ::: "memory");
        } else {
            asm volatile("s_waitcnt vmcnt(0)" ::: "memory");
        }
        __builtin_amdgcn_s_barrier();

        const bf16_t* Asb = As[b];
        const bf16_t* Wsb = Ws[b];
        bf16x8 af[4], bb[4];

        // ---- P0: ks=0, A rows lo + B ----
        {
            const int kxo = (quad * 8) ^ xsw;
#pragma unroll
            for (int i = 0; i < 4; ++i)
                af[i] = *(const bf16x8*)(Asb + aoff + i * 1024 + kxo);
#pragma unroll
            for (int j = 0; j < 4; ++j)
                bb[j] = *(const bf16x8*)(Wsb + boff + j * 1024 + kxo);
        }
        if (pf) lds_stage2(Ab, An, 1024, tid, K, kn);
        __builtin_amdgcn_s_barrier();
        __builtin_amdgcn_s_setprio(1);
#pragma unroll
        for (int i = 0; i < 4; ++i)
#pragma unroll
            for (int j = 0; j < 4; ++j)
                acc[i][j] = MFMA16(af[i], bb[j], acc[i][j]);
        __builtin_amdgcn_s_setprio(0);
        __builtin_amdgcn_s_barrier();

        // ---- P1: ks=0, A rows hi ----
        {
            const int kxo = (quad * 8) ^ xsw;
#pragma unroll
            for (int i = 0; i < 4; ++i)
                af[i] = *(const bf16x8*)(Asb + aoff + (i + 4) * 1024 + kxo);
        }
        if (pf) lds_stage2(Wb, Wn, 0, tid, K, kn);
        __builtin_amdgcn_s_barrier();
        __builtin_amdgcn_s_setprio(1);
#pragma unroll
        for (int i = 0; i < 4; ++i)
#pragma unroll
            for (int j = 0; j < 4; ++j)
                acc[i + 4][j] = MFMA16(af[i], bb[j], acc[i + 4][j]);
        __builtin_amdgcn_s_setprio(0);
        __builtin_amdgcn_s_barrier();

        // ---- P2: ks=1, A rows lo + B ----
        {
            const int kxo = (32 + quad * 8) ^ xsw;
#pragma unroll
            for (int i = 0; i < 4; ++i)
                af[i] = *(const bf16x8*)(Asb + aoff + i * 1024 + kxo);
#pragma unroll
            for (int j = 0; j < 4; ++j)
                bb[j] = *(const bf16x8*)(Wsb + boff + j * 1024 + kxo);
        }
        if (pf) lds_stage2(Wb, Wn, 1024, tid, K, kn);
        __builtin_amdgcn_s_barrier();
        __builtin_amdgcn_s_setprio(1);
#pragma unroll
        for (int i = 0; i < 4; ++i)
#pragma unroll
            for (int j = 0; j < 4; ++j)
                acc[i][j] = MFMA16(af[i], bb[j], acc[i][j]);
        __builtin_amdgcn_s_setprio(0);
        __builtin_amdgcn_s_barrier();

        // ---- P3: ks=1, A rows hi ----
        {
            const int kxo = (32 + quad * 8) ^ xsw;
#pragma unroll
            for (int i = 0; i < 4; ++i)
                af[i] = *(const bf16x8*)(Asb + aoff + (i + 4) * 1024 + kxo);
        }
        __builtin_amdgcn_s_barrier();
        __builtin_amdgcn_s_setprio(1);
#pragma unroll
        for (int i = 0; i < 4; ++i)
#pragma unroll
            for (int j = 0; j < 4; ++j)
                acc[i + 4][j] = MFMA16(af[i], bb[j], acc[i + 4][j]);
        __builtin_amdgcn_s_setprio(0);
        __builtin_amdgcn_s_barrier();
    }

    // epilogue: lane-local SwiGLU. physical 16-col granule parity = j parity
    // (n0, wc*4 even) -> j even = gate, j odd = up, logical col group
    // = n0/32 + wc*2 + j/2.
#pragma unroll
    for (int i = 0; i < 8; ++i)
#pragma unroll
        for (int jp = 0; jp < 2; ++jp)
#pragma unroll
            for (int r = 0; r < 4; ++r) {
                size_t row = (size_t)(m0 + wr * 128 + i * 16 + quad * 4 + r);
                size_t col = (size_t)((n0 >> 1) + wc * 32 + jp * 16 + l16);
                float g = acc[i][2 * jp][r];
                float u = acc[i][2 * jp + 1][r];
                float sig = 1.f / (1.f + __expf(fminf(-g, 80.f)));
                C[row * 5632 + col] = (bf16_t)(g * sig * u);
            }
}

// ---------------------------------------------------------------------------
// 8-phase GEMM, tile 256x128, 8 waves 4Mx2N (per-wave 64x64), 96 KiB dbuf
// LDS, 2 phases/K-tile, counted vmcnt(2). Grid = (M/256)*nbx, %8==0.
// mode 0: Cb=acc | 1: Cb=acc+Rf(f32) | 2: Cf=acc+Rb(bf16)
// ---------------------------------------------------------------------------
__global__ __launch_bounds__(512, 2)
void gemm8(const bf16_t* __restrict__ A, const bf16_t* __restrict__ W,
           const float* __restrict__ Rf, const bf16_t* __restrict__ Rb,
           bf16_t* __restrict__ Cb, float* __restrict__ Cf,
           int M, int N, int K, int nbx, int mode)
{
    __shared__ bf16_t As[2][256 * 64];   // 64 KiB
    __shared__ bf16_t Ws[2][128 * 64];   // 32 KiB

    const int tid  = threadIdx.x;
    const int lane = tid & 63, wave = tid >> 6;
    const int quad = lane >> 4, l16 = lane & 15;
    const int wr = wave >> 1, wc = wave & 1;   // 4M x 2N wave grid

    const int lid = (int)blockIdx.x;
    const int nwg = (M >> 8) * nbx;
    const int q   = nwg >> 3;
    const int swz = (lid & 7) * q + (lid >> 3);
    const int bxn = swz >> 4;
    const int bym = swz & 15;
    const int m0 = bym * 256, n0 = bxn * 128;

    const bf16_t* Ab = A + (size_t)m0 * K;
    const bf16_t* Wb = W + (size_t)n0 * K;

    const int xsw  = (l16 & 7) << 3;
    const int aoff = (wr * 64 + l16) * 64;
    const int boff = (wc * 64 + l16) * 64;

    f32x4 acc[4][4] = {};

    lds_stage2(Ab, As[0], 0,    tid, K, 0);
    lds_stage2(Ab, As[0], 1024, tid, K, 0);
    lds_stage2(Wb, Ws[0], 0,    tid, K, 0);

    const int NT = K >> 6;
    for (int t = 0; t < NT; ++t) {
        const int b  = t & 1;
        const int kn = (t + 1) << 6;
        const bool pf = (t + 1 < NT);
        bf16_t* An = As[1 - b];
        bf16_t* Wn = Ws[1 - b];

        if (pf) {
            lds_stage2(Ab, An, 0, tid, K, kn);
            asm volatile("s_waitcnt vmcnt(2)" ::: "memory");
        } else {
            asm volatile("s_waitcnt vmcnt(0)" ::: "memory");
        }
        __builtin_amdgcn_s_barrier();

        const bf16_t* Asb = As[b];
        const bf16_t* Wsb = Ws[b];

#pragma unroll
        for (int ks = 0; ks < 2; ++ks) {
            const int kxo = (ks * 32 + quad * 8) ^ xsw;
            bf16x8 af[4], bf_[4];
#pragma unroll
            for (int i = 0; i < 4; ++i)
                af[i] = *(const bf16x8*)(Asb + aoff + i * 1024 + kxo);
#pragma unroll
            for (int j = 0; j < 4; ++j)
                bf_[j] = *(const bf16x8*)(Wsb + boff + j * 1024 + kxo);
            if (pf) {
                if (ks == 0) lds_stage2(Ab, An, 1024, tid, K, kn);
                else         lds_stage2(Wb, Wn, 0,    tid, K, kn);
            }
            __builtin_amdgcn_s_barrier();
            __builtin_amdgcn_s_setprio(1);
#pragma unroll
            for (int i = 0; i < 4; ++i)
#pragma unroll
                for (int j = 0; j < 4; ++j)
                    acc[i][j] = MFMA16(af[i], bf_[j], acc[i][j]);
            __builtin_amdgcn_s_setprio(0);
            __builtin_amdgcn_s_barrier();
        }
    }

#pragma unroll
    for (int i = 0; i < 4; ++i)
#pragma unroll
        for (int j = 0; j < 4; ++j)
#pragma unroll
            for (int r = 0; r < 4; ++r) {
                size_t row = (size_t)(m0 + wr * 64 + i * 16 + quad * 4 + r);
                size_t col = (size_t)(n0 + wc * 64 + j * 16 + l16);
                float v = acc[i][j][r];
                if (mode == 1) v += Rf[row * (size_t)N + col];
                if (mode == 2)
                    Cf[row * (size_t)N + col] = v + (float)Rb[row * (size_t)N + col];
                else
                    Cb[row * (size_t)N + col] = (bf16_t)v;
            }
}

// ---------------------------------------------------------------------------
// FALLBACK GEMM (fp32 weights staged in registers)
// ---------------------------------------------------------------------------
__global__ __launch_bounds__(256, 2)
void gemm_bt(const bf16_t* __restrict__ A, const float* __restrict__ W,
             const float* __restrict__ Rf, const bf16_t* __restrict__ Rb,
             bf16_t* __restrict__ Cb, float* __restrict__ Cf,
             int M, int N, int K, int mode)
{
    __shared__ bf16_t As[128 * 64];
    __shared__ bf16_t Ws[128 * 64];

    const int tid  = threadIdx.x;
    const int lane = tid & 63, wave = tid >> 6;
    const int quad = lane >> 4, l16 = lane & 15;
    const int m0 = blockIdx.y * 128, n0 = blockIdx.x * 128;
    const int wm = (wave >> 1) * 64, wn = (wave & 1) * 64;

    f32x4 acc[4][4] = {};

    for (int k0 = 0; k0 < K; k0 += 64) {
        bf16x8 ra[4];
        bf16x4 rw[8];
#pragma unroll
        for (int i = 0; i < 4; ++i) {
            int u = i * 256 + tid;
            int r = u >> 3, c = (u & 7) << 3;
            ra[i] = *(const bf16x8*)(A + (size_t)(m0 + r) * K + k0 + c);
        }
#pragma unroll
        for (int i = 0; i < 8; ++i) {
            int u = i * 256 + tid;
            int r = u >> 4, c = (u & 15) << 2;
            f32x4 w4 = *(const f32x4*)(W + (size_t)(n0 + r) * K + k0 + c);
#pragma unroll
            for (int e = 0; e < 4; ++e) rw[i][e] = (bf16_t)w4[e];
        }
        __syncthreads();
#pragma unroll
        for (int i = 0; i < 4; ++i)
            *(bf16x8*)(As + (i * 256 + tid) * 8) = ra[i];
#pragma unroll
        for (int i = 0; i < 8; ++i)
            *(bf16x4*)(Ws + (i * 256 + tid) * 4) = rw[i];
        __syncthreads();

#pragma unroll
        for (int ks = 0; ks < 64; ks += 32) {
            bf16x8 af[4], bfr[4];
#pragma unroll
            for (int i = 0; i < 4; ++i)
                af[i] = *(const bf16x8*)(As + (wm + i * 16 + l16) * 64 + ks + quad * 8);
#pragma unroll
            for (int j = 0; j < 4; ++j)
                bfr[j] = *(const bf16x8*)(Ws + (wn + j * 16 + l16) * 64 + ks + quad * 8);
#pragma unroll
            for (int i = 0; i < 4; ++i)
#pragma unroll
                for (int j = 0; j < 4; ++j)
                    acc[i][j] = MFMA16(af[i], bfr[j], acc[i][j]);
        }
    }

#pragma unroll
    for (int i = 0; i < 4; ++i)
#pragma unroll
        for (int j = 0; j < 4; ++j)
#pragma unroll
            for (int r = 0; r < 4; ++r) {
                size_t row = (size_t)(m0 + wm + i * 16 + quad * 4 + r);
                size_t col = (size_t)(n0 + wn + j * 16 + l16);
                float v = acc[i][j][r];
                if (mode == 1) v += Rf[row * (size_t)N + col];
                if (mode == 2)
                    Cf[row * (size_t)N + col] = v + (float)Rb[row * (size_t)N + col];
                else
                    Cb[row * (size_t)N + col] = (bf16_t)v;
            }
}

// ---------------------------------------------------------------------------
// FALLBACK fused gate+up (fp32 weights)
// ---------------------------------------------------------------------------
__global__ __launch_bounds__(256, 2)
void gemm_gateup(const bf16_t* __restrict__ A, const float* __restrict__ G,
                 const float* __restrict__ U, bf16_t* __restrict__ C,
                 int M, int N, int K)
{
    __shared__ bf16_t As[128 * 64];
    __shared__ bf16_t Gs[128 * 64];
    __shared__ bf16_t Us[128 * 64];

    const int tid  = threadIdx.x;
    const int lane = tid & 63, wave = tid >> 6;
    const int quad = lane >> 4, l16 = lane & 15;
    const int m0 = blockIdx.y * 128, n0 = blockIdx.x * 128;
    const int wm = (wave >> 1) * 64, wn = (wave & 1) * 64;

    f32x4 accg[4][4] = {};
    f32x4 accu[4][4] = {};

    for (int k0 = 0; k0 < K; k0 += 64) {
        bf16x8 ra[4];
        bf16x4 rg[8], ru[8];
#pragma unroll
        for (int i = 0; i < 4; ++i) {
            int u = i * 256 + tid;
            int r = u >> 3, c = (u & 7) << 3;
            ra[i] = *(const bf16x8*)(A + (size_t)(m0 + r) * K + k0 + c);
        }
#pragma unroll
        for (int i = 0; i < 8; ++i) {
            int u = i * 256 + tid;
            int r = u >> 4, c = (u & 15) << 2;
            f32x4 g4 = *(const f32x4*)(G + (size_t)(n0 + r) * K + k0 + c);
            f32x4 u4 = *(const f32x4*)(U + (size_t)(n0 + r) * K + k0 + c);
#pragma unroll
            for (int e = 0; e < 4; ++e) { rg[i][e] = (bf16_t)g4[e]; ru[i][e] = (bf16_t)u4[e]; }
        }
        __syncthreads();
#pragma unroll
        for (int i = 0; i < 4; ++i)
            *(bf16x8*)(As + (i * 256 + tid) * 8) = ra[i];
#pragma unroll
        for (int i = 0; i < 8; ++i) {
            *(bf16x4*)(Gs + (i * 256 + tid) * 4) = rg[i];
            *(bf16x4*)(Us + (i * 256 + tid) * 4) = ru[i];
        }
        __syncthreads();

#pragma unroll
        for (int ks = 0; ks < 64; ks += 32) {
            bf16x8 af[4], bg[4], bu[4];
#pragma unroll
            for (int i = 0; i < 4; ++i)
                af[i] = *(const bf16x8*)(As + (wm + i * 16 + l16) * 64 + ks + quad * 8);
#pragma unroll
            for (int j = 0; j < 4; ++j) {
                bg[j] = *(const bf16x8*)(Gs + (wn + j * 16 + l16) * 64 + ks + quad * 8);
                bu[j] = *(const bf16x8*)(Us + (wn + j * 16 + l16) * 64 + ks + quad * 8);
            }
#pragma unroll
            for (int i = 0; i < 4; ++i)
#pragma unroll
                for (int j = 0; j < 4; ++j) {
                    accg[i][j] = MFMA16(af[i], bg[j], accg[i][j]);
                    accu[i][j] = MFMA16(af[i], bu[j], accu[i][j]);
                }
        }
    }

#pragma unroll
    for (int i = 0; i < 4; ++i)
#pragma unroll
        for (int j = 0; j < 4; ++j)
#pragma unroll
            for (int r = 0; r < 4; ++r) {
                size_t row = (size_t)(m0 + wm + i * 16 + quad * 4 + r);
                size_t col = (size_t)(n0 + wn + j * 16 + l16);
                float g = accg[i][j][r];
                float u = accu[i][j][r];
                float sig = 1.f / (1.f + __expf(fminf(-g, 80.f)));
                C[row * (size_t)N + col] = (bf16_t)(g * sig * u);
            }
}

// ---------------------------------------------------------------------------
// Flash attention fwd (round-4 structure + diagonal-only mask + setprio).
// kvs = row stride of K/V buffers (1024 = separate contiguous buffers).
// ---------------------------------------------------------------------------
__global__ __launch_bounds__(256, 2)
void attn_fwd(const bf16_t* __restrict__ Q, const bf16_t* __restrict__ Kg,
              const bf16_t* __restrict__ Vg, bf16_t* __restrict__ O, int kvs)
{
    __shared__ bf16_t Ks[2][64 * 128];   // col XOR-swizzled by (row&7)<<3
    __shared__ bf16_t Vt[2][128 * 64];   // Vt[d][kb], slot = kb^(d&7)
    __shared__ bf16_t Pl[4][16 * 72];    // padded stride 72

    const int tid  = threadIdx.x;
    const int lane = tid & 63, wave = tid >> 6;
    const int quad = lane >> 4, l16 = lane & 15;
    const int bh = blockIdx.y, b = bh >> 4, h = bh & 15;

    const bf16_t* Qh = Q  + (size_t)b * 2048 * 2048 + (size_t)h * 128;
    const bf16_t* Kh = Kg + (size_t)b * 2048 * kvs + (size_t)(h >> 1) * 128;
    const bf16_t* Vh = Vg + (size_t)b * 2048 * kvs + (size_t)(h >> 1) * 128;

    const float scale = 0.08838834764831845f;   // 1/sqrt(128)

    const int krow = tid >> 4;            // K row within 16-row group
    const int kcol = (tid & 15) << 3;     // K col (8-elem granule)
    const int vd   = tid & 127;           // V transpose: d
    const int vkb  = tid >> 7;            // V transpose: kb base (+2*it)

#pragma unroll 1
    for (int pass = 0; pass < 2; ++pass) {
        const int qt = pass ? (31 - (int)blockIdx.x) : (int)blockIdx.x;
        const int q0 = qt * 64;

        bf16x8 aq[4];
#pragma unroll
        for (int ks = 0; ks < 4; ++ks)
            aq[ks] = *(const bf16x8*)(Qh + (size_t)(q0 + wave * 16 + l16) * 2048 + ks * 32 + quad * 8);

        float m_r[4] = { -30000.f, -30000.f, -30000.f, -30000.f };
        float l_r[4] = { 0.f, 0.f, 0.f, 0.f };
        f32x4 acc_o[8] = {};

        const int ntiles = qt + 1;

        bf16x8 rk[4], rv[4];
        // ---- prologue: stage tile 0 into buf 0 ----
#pragma unroll
        for (int i = 0; i < 4; ++i)
            rk[i] = *(const bf16x8*)(Kh + (size_t)(i * 16 + krow) * kvs + kcol);
#pragma unroll
        for (int it = 0; it < 4; ++it)
#pragma unroll
            for (int j = 0; j < 8; ++j)
                rv[it][j] = Vh[(size_t)((vkb + 2 * it) * 8 + j) * kvs + vd];
#pragma unroll
        for (int i = 0; i < 4; ++i) {
            int row = i * 16 + krow;
            *(bf16x8*)(&Ks[0][row * 128 + (kcol ^ ((row & 7) << 3))]) = rk[i];
        }
#pragma unroll
        for (int it = 0; it < 4; ++it) {
            int kb = vkb + 2 * it;
            *(bf16x8*)(&Vt[0][vd * 64 + ((kb ^ (vd & 7)) << 3)]) = rv[it];
        }
        __syncthreads();

        for (int t = 0; t < ntiles; ++t) {
            const int bb = t & 1;
            const bool pf = (t + 1 < ntiles);
            const bool diag = (t == qt);
            const int kv0 = t * 64;
            const int kvn = kv0 + 64;

            if (pf) {   // early-issue next tile's global loads (regs)
#pragma unroll
                for (int i = 0; i < 4; ++i)
                    rk[i] = *(const bf16x8*)(Kh + (size_t)(kvn + i * 16 + krow) * kvs + kcol);
#pragma unroll
                for (int it = 0; it < 4; ++it)
#pragma unroll
                    for (int j = 0; j < 8; ++j)
                        rv[it][j] = Vh[(size_t)(kvn + (vkb + 2 * it) * 8 + j) * kvs + vd];
            }

            // ---- QK^T (swizzled Ks reads, conflict-free) ----
            f32x4 accs[4] = {};
            __builtin_amdgcn_s_setprio(1);
#pragma unroll
            for (int ks = 0; ks < 4; ++ks)
#pragma unroll
                for (int j = 0; j < 4; ++j) {
                    const int row = j * 16 + l16;
                    bf16x8 bk = *(const bf16x8*)(&Ks[bb][row * 128 + ((ks * 32 + quad * 8) ^ ((row & 7) << 3))]);
                    accs[j] = MFMA16(aq[ks], bk, accs[j]);
                }
            __builtin_amdgcn_s_setprio(0);

            // ---- online softmax (mask only on the diagonal tile) ----
#pragma unroll
            for (int r = 0; r < 4; ++r) {
                const int qrow = q0 + wave * 16 + quad * 4 + r;
                float s[4];
#pragma unroll
                for (int j = 0; j < 4; ++j) s[j] = accs[j][r] * scale;
                if (diag) {
#pragma unroll
                    for (int j = 0; j < 4; ++j)
                        if (kv0 + j * 16 + l16 > qrow) s[j] = -30000.f;
                }
                float mx = fmaxf(fmaxf(s[0], s[1]), fmaxf(s[2], s[3]));
                mx = fmaxf(mx, __shfl_xor(mx, 1, 64));
                mx = fmaxf(mx, __shfl_xor(mx, 2, 64));
                mx = fmaxf(mx, __shfl_xor(mx, 4, 64));
                mx = fmaxf(mx, __shfl_xor(mx, 8, 64));
                float mnew  = fmaxf(m_r[r], mx);
                float alpha = __expf(fmaxf(m_r[r] - mnew, -80.f));
                float rs = 0.f;
#pragma unroll
                for (int j = 0; j < 4; ++j) {
                    float p = __expf(fmaxf(s[j] - mnew, -80.f));
                    rs += p;
                    Pl[wave][(quad * 4 + r) * 72 + j * 16 + l16] = (bf16_t)p;
                }
                rs += __shfl_xor(rs, 1, 64);
                rs += __shfl_xor(rs, 2, 64);
                rs += __shfl_xor(rs, 4, 64);
                rs += __shfl_xor(rs, 8, 64);
                l_r[r] = l_r[r] * alpha + rs;
                m_r[r] = mnew;
#pragma unroll
                for (int nt = 0; nt < 8; ++nt) acc_o[nt][r] *= alpha;
            }

            // ---- PV (Pl is per-wave; compiler orders via lgkmcnt) ----
            __builtin_amdgcn_s_setprio(1);
#pragma unroll
            for (int ks2 = 0; ks2 < 2; ++ks2) {
                bf16x8 ap = *(const bf16x8*)(&Pl[wave][l16 * 72 + ks2 * 32 + quad * 8]);
                const int kb_r = ks2 * 4 + quad;
#pragma unroll
                for (int nt = 0; nt < 8; ++nt) {
                    const int d = nt * 16 + l16;
                    bf16x8 bv = *(const bf16x8*)(&Vt[bb][d * 64 + ((kb_r ^ (d & 7)) << 3)]);
                    acc_o[nt] = MFMA16(ap, bv, acc_o[nt]);
                }
            }
            __builtin_amdgcn_s_setprio(0);

            // ---- write prefetched tile into the other buffer ----
            if (pf) {
#pragma unroll
                for (int i = 0; i < 4; ++i) {
                    int row = i * 16 + krow;
                    *(bf16x8*)(&Ks[1 - bb][row * 128 + (kcol ^ ((row & 7) << 3))]) = rk[i];
                }
#pragma unroll
                for (int it = 0; it < 4; ++it) {
                    int kb = vkb + 2 * it;
                    *(bf16x8*)(&Vt[1 - bb][vd * 64 + ((kb ^ (vd & 7)) << 3)]) = rv[it];
                }
            }
            __syncthreads();   // buf[1-bb] writes visible; joint advance
        }

#pragma unroll
        for (int r = 0; r < 4; ++r) {
            float inv = 1.f / fmaxf(l_r[r], 1e-30f);
            size_t orow = (size_t)b * 2048 + q0 + wave * 16 + quad * 4 + r;
#pragma unroll
            for (int nt = 0; nt < 8; ++nt)
                O[orow * 2048 + h * 128 + nt * 16 + l16] = (bf16_t)(acc_o[nt][r] * inv);
        }
    }
}

// ---------------------------------------------------------------------------
// Launch. Fast path (ws >= 174 MB): single wconv (with gate/up interleave),
// gemm_qkv, attn, gemm8 O, gateup_il (2-operand 256^2 GEMM), gemm8 down.
// 8 dispatches. Fallback: fp32-weight path. Branch on ws_size.
// ---------------------------------------------------------------------------
extern "C" void kernel_launch(void* const* d_in, const int* in_sizes, int n_in,
                              void* d_out, int out_size, void* d_ws, size_t ws_size,
                              hipStream_t stream)
{
    const float* x   = (const float*)d_in[0];
    const float* qw  = (const float*)d_in[2];
    const float* kw  = (const float*)d_in[3];
    const float* vw  = (const float*)d_in[4];
    const float* ow  = (const float*)d_in[5];
    const float* gw  = (const float*)d_in[6];
    const float* uw  = (const float*)d_in[7];
    const float* dw  = (const float*)d_in[8];
    const float* ln1 = (const float*)d_in[9];
    const float* ln2 = (const float*)d_in[10];
    float*  out = (float*)d_out;
    bf16_t* ws  = (bf16_t*)d_ws;

    dim3 blk(256);
    const size_t NEED = 87031808ull * 2;   // 174 MB

    if (ws_size >= NEED) {
        // ---- fast path: bf16 weights + async-staged GEMMs ----
        bf16_t* wq  = ws;                     // 4,194,304  (wq||wk||wv = QKV W)
        bf16_t* wo  = ws + 8388608;           // 4,194,304
        bf16_t* wgu = ws + 12582912;          // 23,068,672 (interleaved gate/up)
        bf16_t* wd  = ws + 35651584;          // 11,534,336
        bf16_t* h1  = ws + 47185920;          // 8,388,608
        bf16_t* qb  = ws + 55574528;          // 8,388,608 (later hb)
        bf16_t* kb  = ws + 63963136;          // 4,194,304 (later gb)
        bf16_t* vb  = ws + 68157440;          // 4,194,304
        bf16_t* ab  = (bf16_t*)d_out;         // attn out scratch in d_out
        bf16_t* hb  = qb;
        bf16_t* gb  = kb;                     // 23,068,672 ends at 87,031,808

        wconv_all<<<23040, blk, 0, stream>>>(qw, kw, vw, ow, gw, uw, dw, ws);
        rmsnorm_f32<<<4096, blk, 0, stream>>>(x, ln1, h1);
        gemm_qkv<<<256, dim3(512), 0, stream>>>(h1, wq, qb, kb, vb, 2048);
        attn_fwd<<<dim3(16, 32), blk, 0, stream>>>(qb, kb, vb, ab, 1024);
        gemm8<<<256, dim3(512), 0, stream>>>(ab, wo, x, nullptr, hb, nullptr, 4096, 2048, 2048, 16, 1);
        rmsnorm_bf16<<<4096, blk, 0, stream>>>(hb, ln2, h1);
        gateup_il<<<704, dim3(512), 0, stream>>>(h1, wgu, gb, 2048);
        gemm8<<<256, dim3(512), 0, stream>>>(gb, wd, nullptr, hb, nullptr, out, 4096, 2048, 5632, 16, 2);
    } else {
        // ---- fallback: fp32-weight path (78 MB) ----
        const size_t ME = 1ull << 20;
        bf16_t* h1 = ws;
        bf16_t* qb = ws + 8  * ME;
        bf16_t* kb = ws + 16 * ME;
        bf16_t* vb = ws + 20 * ME;
        bf16_t* ab = (bf16_t*)d_out;
        bf16_t* hb = ws + 8  * ME;
        bf16_t* gb = ws + 16 * ME;

        rmsnorm_f32<<<4096, blk, 0, stream>>>(x, ln1, h1);
        gemm_bt<<<dim3(16, 32), blk, 0, stream>>>(h1, qw, nullptr, nullptr, qb, nullptr, 4096, 2048, 2048, 0);
        gemm_bt<<<dim3( 8, 32), blk, 0, stream>>>(h1, kw, nullptr, nullptr, kb, nullptr, 4096, 1024, 2048, 0);
        gemm_bt<<<dim3( 8, 32), blk, 0, stream>>>(h1, vw, nullptr, nullptr, vb, nullptr, 4096, 1024, 2048, 0);
        attn_fwd<<<dim3(16, 32), blk, 0, stream>>>(qb, kb, vb, ab, 1024);
        gemm_bt<<<dim3(16, 32), blk, 0, stream>>>(ab, ow, x, nullptr, hb, nullptr, 4096, 2048, 2048, 1);
        rmsnorm_bf16<<<4096, blk, 0, stream>>>(hb, ln2, h1);
        gemm_gateup<<<dim3(44, 32), blk, 0, stream>>>(h1, gw, uw, gb, 4096, 5632, 2048);
        gemm_bt<<<dim3(16, 32), blk, 0, stream>>>(gb, dw, nullptr, hb, nullptr, out, 4096, 2048, 5632, 2);
    }
}